// Round 1
// baseline (1961.121 us; speedup 1.0000x reference)
//
#include <hip/hip_runtime.h>
#include <hip/hip_bf16.h>
#include <math.h>

#define NNODES 20000
#define NEDGES 640000
#define BSZ 256
#define GDIM 256
#define HID 512
#define INNER 2048
#define RANK 512
#define NCLS 3
#define NGENES 6640

// ---------------- CSR build (per launch; inputs restored every call) ----------------
__global__ void hist_k(const int* __restrict__ dst, int* __restrict__ counts, int E) {
    int e = blockIdx.x * 256 + threadIdx.x;
    if (e < E) atomicAdd(&counts[dst[e]], 1);
}

__global__ void scan1_k(const int* __restrict__ counts, int* __restrict__ incl,
                        int* __restrict__ bsums, int n) {
    __shared__ int s[256];
    int i = blockIdx.x * 256 + threadIdx.x;
    int v = (i < n) ? counts[i] : 0;
    s[threadIdx.x] = v;
    __syncthreads();
    for (int off = 1; off < 256; off <<= 1) {
        int t = (threadIdx.x >= off) ? s[threadIdx.x - off] : 0;
        __syncthreads();
        s[threadIdx.x] += t;
        __syncthreads();
    }
    if (i < n) incl[i] = s[threadIdx.x];
    if (threadIdx.x == 255) bsums[blockIdx.x] = s[255];
}

__global__ void scan2_k(const int* __restrict__ bsums, int* __restrict__ boffs, int nb) {
    __shared__ int s[128];
    int tid = threadIdx.x;
    int v = (tid < nb) ? bsums[tid] : 0;
    s[tid] = v;
    __syncthreads();
    for (int off = 1; off < 128; off <<= 1) {
        int t = (tid >= off) ? s[tid - off] : 0;
        __syncthreads();
        s[tid] += t;
        __syncthreads();
    }
    if (tid < nb) boffs[tid] = s[tid] - v;   // exclusive
}

__global__ void scan3_k(const int* __restrict__ incl, const int* __restrict__ counts,
                        const int* __restrict__ boffs, int* __restrict__ row_start,
                        int* __restrict__ cursor, int n) {
    int i = blockIdx.x * 256 + threadIdx.x;
    if (i < n) {
        int st = incl[i] - counts[i] + boffs[blockIdx.x];
        row_start[i] = st;
        cursor[i] = st;
    }
}

__global__ void scatter_k(const int* __restrict__ src, const int* __restrict__ dst,
                          const float* __restrict__ w, int* __restrict__ cursor,
                          int* __restrict__ es, float* __restrict__ ew, int E) {
    int e = blockIdx.x * 256 + threadIdx.x;
    if (e < E) {
        int d = dst[e];
        int p = atomicAdd(&cursor[d], 1);
        es[p] = src[e];
        ew[p] = w[e];
    }
}

// ---------------- LayerNorm: one wave per row, D = 256*VPL ----------------
template <int VPL>
__global__ void ln_k(const float* __restrict__ X, const float* __restrict__ sc,
                     const float* __restrict__ bi, float* __restrict__ Y, int M) {
    const int D = 256 * VPL;
    int row = blockIdx.x * 4 + (threadIdx.x >> 6);
    int lane = threadIdx.x & 63;
    if (row >= M) return;
    const float4* xp = (const float4*)(X + (size_t)row * D);
    float4 v[VPL];
    float sum = 0.f;
#pragma unroll
    for (int i = 0; i < VPL; i++) {
        v[i] = xp[i * 64 + lane];
        sum += v[i].x + v[i].y + v[i].z + v[i].w;
    }
#pragma unroll
    for (int off = 32; off >= 1; off >>= 1) sum += __shfl_xor(sum, off);
    float mu = sum / D;
    float sq = 0.f;
#pragma unroll
    for (int i = 0; i < VPL; i++) {
        float a = v[i].x - mu, b = v[i].y - mu, c = v[i].z - mu, d = v[i].w - mu;
        sq += a * a + b * b + c * c + d * d;
    }
#pragma unroll
    for (int off = 32; off >= 1; off >>= 1) sq += __shfl_xor(sq, off);
    float rstd = rsqrtf(sq / D + 1e-5f);
    float4* yp = (float4*)(Y + (size_t)row * D);
    const float4* sp = (const float4*)sc;
    const float4* bp = (const float4*)bi;
#pragma unroll
    for (int i = 0; i < VPL; i++) {
        float4 s4 = sp[i * 64 + lane], b4 = bp[i * 64 + lane];
        float4 o;
        o.x = (v[i].x - mu) * rstd * s4.x + b4.x;
        o.y = (v[i].y - mu) * rstd * s4.y + b4.y;
        o.z = (v[i].z - mu) * rstd * s4.z + b4.z;
        o.w = (v[i].w - mu) * rstd * s4.w + b4.w;
        yp[i * 64 + lane] = o;
    }
}

// ---------------- CSR aggregation: one wave per dst row ----------------
__global__ void agg_k(const int* __restrict__ row_start, const int* __restrict__ counts,
                      const int* __restrict__ es, const float* __restrict__ ew,
                      const float* __restrict__ H, float* __restrict__ AGG, int n) {
    int row = blockIdx.x * 4 + (threadIdx.x >> 6);
    int lane = threadIdx.x & 63;
    if (row >= n) return;
    int beg = row_start[row], cnt = counts[row];
    float ax = 0.f, ay = 0.f, az = 0.f, aw = 0.f;
    for (int t = 0; t < cnt; t++) {
        int s = es[beg + t];
        float w = ew[beg + t];
        float4 v = *(const float4*)(H + (size_t)s * GDIM + lane * 4);
        ax = fmaf(v.x, w, ax);
        ay = fmaf(v.y, w, ay);
        az = fmaf(v.z, w, az);
        aw = fmaf(v.w, w, aw);
    }
    float4 o = {ax, ay, az, aw};
    *(float4*)(AGG + (size_t)row * GDIM + lane * 4) = o;
}

// ---------------- Generic tiled fp32 GEMM with fused epilogue ----------------
// C[M,N] = epilogue(A[M,K] @ B)  where B is [K,N] row-major (BT=false) or [N,K] (BT=true).
// ACT: 0=none, 1=relu, 2=gelu(exact). RES: C = act(A@B+bias) + R.
#define TM 64
#define TN 64
#define BKK 32

template <int ACT, bool BT, bool RES, bool BIAS>
__global__ __launch_bounds__(256) void gemm_k(const float* __restrict__ A,
                                              const float* __restrict__ B,
                                              const float* __restrict__ bias,
                                              const float* __restrict__ R,
                                              float* __restrict__ C, int M, int N, int K) {
    __shared__ __align__(16) float As[BKK][TM + 4];  // A^T chunk: As[k][m]
    __shared__ __align__(16) float Bs[BKK][TN + 4];  // Bs[k][n]
    int m0 = blockIdx.y * TM;
    int n0 = blockIdx.x * TN;
    int tid = threadIdx.x;
    int tr = tid >> 4;   // 0..15 -> rows tr*4..tr*4+3
    int tc = tid & 15;   // 0..15 -> cols tc*4..tc*4+3
    float acc[4][4] = {};

    for (int k0 = 0; k0 < K; k0 += BKK) {
        // stage A^T
        {
            int r = tid >> 3;       // 0..31
            int kq = tid & 7;       // k quad
#pragma unroll
            for (int p = 0; p < 2; p++) {
                int rr = r + p * 32;
                int gm = m0 + rr;
                float4 v = {0.f, 0.f, 0.f, 0.f};
                if (gm < M) v = *(const float4*)(A + (size_t)gm * K + k0 + kq * 4);
                As[kq * 4 + 0][rr] = v.x;
                As[kq * 4 + 1][rr] = v.y;
                As[kq * 4 + 2][rr] = v.z;
                As[kq * 4 + 3][rr] = v.w;
            }
        }
        // stage B
        if constexpr (!BT) {
            int kk = tid >> 4;      // 0..15
            int c4 = (tid & 15) * 4;
#pragma unroll
            for (int p = 0; p < 2; p++) {
                int kkk = kk + p * 16;
                int gn = n0 + c4;
                float4 v = {0.f, 0.f, 0.f, 0.f};
                if (gn < N) v = *(const float4*)(B + (size_t)(k0 + kkk) * N + gn);
                *(float4*)&Bs[kkk][c4] = v;
            }
        } else {
            int g = tid >> 3;       // 0..31
            int kq = tid & 7;
#pragma unroll
            for (int p = 0; p < 2; p++) {
                int gg = g + p * 32;
                int gn = n0 + gg;
                float4 v = {0.f, 0.f, 0.f, 0.f};
                if (gn < N) v = *(const float4*)(B + (size_t)gn * K + k0 + kq * 4);
                Bs[kq * 4 + 0][gg] = v.x;
                Bs[kq * 4 + 1][gg] = v.y;
                Bs[kq * 4 + 2][gg] = v.z;
                Bs[kq * 4 + 3][gg] = v.w;
            }
        }
        __syncthreads();
#pragma unroll
        for (int kk = 0; kk < BKK; kk++) {
            float4 av = *(const float4*)&As[kk][tr * 4];
            float4 bv = *(const float4*)&Bs[kk][tc * 4];
            acc[0][0] = fmaf(av.x, bv.x, acc[0][0]);
            acc[0][1] = fmaf(av.x, bv.y, acc[0][1]);
            acc[0][2] = fmaf(av.x, bv.z, acc[0][2]);
            acc[0][3] = fmaf(av.x, bv.w, acc[0][3]);
            acc[1][0] = fmaf(av.y, bv.x, acc[1][0]);
            acc[1][1] = fmaf(av.y, bv.y, acc[1][1]);
            acc[1][2] = fmaf(av.y, bv.z, acc[1][2]);
            acc[1][3] = fmaf(av.y, bv.w, acc[1][3]);
            acc[2][0] = fmaf(av.z, bv.x, acc[2][0]);
            acc[2][1] = fmaf(av.z, bv.y, acc[2][1]);
            acc[2][2] = fmaf(av.z, bv.z, acc[2][2]);
            acc[2][3] = fmaf(av.z, bv.w, acc[2][3]);
            acc[3][0] = fmaf(av.w, bv.x, acc[3][0]);
            acc[3][1] = fmaf(av.w, bv.y, acc[3][1]);
            acc[3][2] = fmaf(av.w, bv.z, acc[3][2]);
            acc[3][3] = fmaf(av.w, bv.w, acc[3][3]);
        }
        __syncthreads();
    }

#pragma unroll
    for (int i = 0; i < 4; i++) {
        int gm = m0 + tr * 4 + i;
        if (gm >= M) continue;
#pragma unroll
        for (int j = 0; j < 4; j++) {
            int gn = n0 + tc * 4 + j;
            if (gn >= N) continue;
            float v = acc[i][j];
            if (BIAS) v += bias[gn];
            if (ACT == 1) v = fmaxf(v, 0.f);
            if (ACT == 2) v = 0.5f * v * (1.f + erff(v * 0.70710678118654752f));
            if (RES) v += R[(size_t)gm * N + gn];
            C[(size_t)gm * N + gn] = v;
        }
    }
}

// ---------------- OOV-safe gather / fixup ----------------
__global__ void gather_k(const int* __restrict__ idx, const float* __restrict__ X,
                         float* __restrict__ Y) {
    int b = blockIdx.x;
    int lane = threadIdx.x;
    int id = idx[b];
    int safe = id < 0 ? 0 : id;
    float4 v = *(const float4*)(X + (size_t)safe * GDIM + lane * 4);
    *(float4*)(Y + (size_t)b * GDIM + lane * 4) = v;
}

__global__ void oovfix_k(const int* __restrict__ idx, const float* __restrict__ oov_emb,
                         float* __restrict__ P) {
    int b = blockIdx.x;
    int lane = threadIdx.x;
    if (idx[b] < 0) {
        *(float4*)(P + (size_t)b * GDIM + lane * 4) = ((const float4*)oov_emb)[lane];
    }
}

// ---------------- launch ----------------
extern "C" void kernel_launch(void* const* d_in, const int* in_sizes, int n_in,
                              void* d_out, int out_size, void* d_ws, size_t ws_size,
                              hipStream_t stream) {
    const int* node_indices = (const int*)d_in[0];
    const int* edge_src = (const int*)d_in[1];
    const int* edge_dst = edge_src + NEDGES;
    const float* edge_w = (const float*)d_in[2];
    const float* partial_emb = (const float*)d_in[3];
    const float* oov_emb = (const float*)d_in[4];
    const float* gnn_ln_s = (const float*)d_in[5];
    const float* gnn_ln_b = (const float*)d_in[6];
    const float* gnn_w = (const float*)d_in[7];
    const float* gnn_b = (const float*)d_in[8];
    const float* post_w = (const float*)d_in[9];
    const float* post_b = (const float*)d_in[10];
    const float* pin_w = (const float*)d_in[11];
    const float* pin_b = (const float*)d_in[12];
    const float* blk_ln_s = (const float*)d_in[13];
    const float* blk_ln_b = (const float*)d_in[14];
    const float* blk_w1 = (const float*)d_in[15];
    const float* blk_b1 = (const float*)d_in[16];
    const float* blk_w2 = (const float*)d_in[17];
    const float* blk_b2 = (const float*)d_in[18];
    const float* pout_w = (const float*)d_in[19];
    const float* pout_b = (const float*)d_in[20];
    const float* gene = (const float*)d_in[21];
    float* out = (float*)d_out;

    char* p = (char*)d_ws;
    auto alloc = [&](size_t bytes) {
        char* r = p;
        p += (bytes + 255) & ~(size_t)255;
        return r;
    };
    int* counts = (int*)alloc(NNODES * 4);
    int* incl = (int*)alloc(NNODES * 4);
    int* bsums = (int*)alloc(128 * 4);
    int* boffs = (int*)alloc(128 * 4);
    int* row_start = (int*)alloc(NNODES * 4);
    int* cursor = (int*)alloc(NNODES * 4);
    int* es = (int*)alloc((size_t)NEDGES * 4);
    float* ew = (float*)alloc((size_t)NEDGES * 4);
    float* ln_buf = (float*)alloc((size_t)NNODES * GDIM * 4);
    float* aggb = (float*)alloc((size_t)NNODES * GDIM * 4);
    float* xa = (float*)alloc((size_t)NNODES * GDIM * 4);
    float* xb = (float*)alloc((size_t)NNODES * GDIM * 4);
    float* pert_in = (float*)alloc((size_t)BSZ * GDIM * 4);
    float* pertA = (float*)alloc((size_t)BSZ * GDIM * 4);
    float* hbuf = (float*)alloc((size_t)BSZ * HID * 4);
    float* zln = (float*)alloc((size_t)BSZ * HID * 4);
    float* z1 = (float*)alloc((size_t)BSZ * INNER * 4);
    float* proj = (float*)alloc((size_t)BSZ * NCLS * RANK * 4);

    const int EB = (NEDGES + 255) / 256;                 // 2500
    const int NB = (NNODES + 255) / 256;                 // 79

    // CSR build
    hipMemsetAsync(counts, 0, NNODES * 4, stream);
    hist_k<<<EB, 256, 0, stream>>>(edge_dst, counts, NEDGES);
    scan1_k<<<NB, 256, 0, stream>>>(counts, incl, bsums, NNODES);
    scan2_k<<<1, 128, 0, stream>>>(bsums, boffs, NB);
    scan3_k<<<NB, 256, 0, stream>>>(incl, counts, boffs, row_start, cursor, NNODES);
    scatter_k<<<EB, 256, 0, stream>>>(edge_src, edge_dst, edge_w, cursor, es, ew, NEDGES);

    // GNN tail: 3 layers
    const float* x_in = partial_emb;
    float* bufs[2] = {xa, xb};
    for (int i = 0; i < 3; i++) {
        ln_k<1><<<(NNODES + 3) / 4, 256, 0, stream>>>(x_in, gnn_ln_s + i * GDIM,
                                                      gnn_ln_b + i * GDIM, ln_buf, NNODES);
        agg_k<<<(NNODES + 3) / 4, 256, 0, stream>>>(row_start, counts, es, ew, ln_buf, aggb,
                                                    NNODES);
        float* x_out = bufs[i & 1];
        gemm_k<1, false, true, true><<<dim3(GDIM / TN, (NNODES + TM - 1) / TM), 256, 0, stream>>>(
            aggb, gnn_w + (size_t)i * GDIM * GDIM, gnn_b + i * GDIM, x_in, x_out, NNODES, GDIM,
            GDIM);
        x_in = x_out;
    }

    // gather + post_mp + OOV fixup
    gather_k<<<BSZ, 64, 0, stream>>>(node_indices, x_in, pert_in);
    gemm_k<0, false, false, true><<<dim3(GDIM / TN, BSZ / TM), 256, 0, stream>>>(
        pert_in, post_w, post_b, nullptr, pertA, BSZ, GDIM, GDIM);
    oovfix_k<<<BSZ, 64, 0, stream>>>(node_indices, oov_emb, pertA);

    // bilinear head
    gemm_k<0, false, false, true><<<dim3(HID / TN, BSZ / TM), 256, 0, stream>>>(
        pertA, pin_w, pin_b, nullptr, hbuf, BSZ, HID, GDIM);
    for (int i = 0; i < 6; i++) {
        ln_k<2><<<BSZ / 4, 256, 0, stream>>>(hbuf, blk_ln_s + i * HID, blk_ln_b + i * HID, zln,
                                             BSZ);
        gemm_k<2, false, false, true><<<dim3(INNER / TN, BSZ / TM), 256, 0, stream>>>(
            zln, blk_w1 + (size_t)i * HID * INNER, blk_b1 + i * INNER, nullptr, z1, BSZ, INNER,
            HID);
        gemm_k<0, false, true, true><<<dim3(HID / TN, BSZ / TM), 256, 0, stream>>>(
            z1, blk_w2 + (size_t)i * INNER * HID, blk_b2 + i * HID, hbuf, hbuf, BSZ, HID, INNER);
    }
    gemm_k<0, false, false, true><<<dim3((NCLS * RANK) / TN, BSZ / TM), 256, 0, stream>>>(
        hbuf, pout_w, pout_b, nullptr, proj, BSZ, NCLS * RANK, HID);

    // logits: [768,512] @ gene[6640,512]^T
    gemm_k<0, true, false, false><<<dim3((NGENES + TN - 1) / TN, (BSZ * NCLS + TM - 1) / TM), 256,
                                    0, stream>>>(proj, gene, nullptr, nullptr, out, BSZ * NCLS,
                                                 NGENES, RANK);
}

// Round 2
// 1043.069 us; speedup vs baseline: 1.8801x; 1.8801x over previous
//
#include <hip/hip_runtime.h>
#include <hip/hip_bf16.h>
#include <math.h>

#define NNODES 20000
#define NEDGES 640000
#define BSZ 256
#define GDIM 256
#define HID 512
#define INNER 2048
#define RANK 512
#define NCLS 3
#define NGENES 6640

// ---------------- CSR build (per launch; inputs restored every call) ----------------
__global__ void hist_k(const int* __restrict__ dst, int* __restrict__ counts, int E) {
    int e = blockIdx.x * 256 + threadIdx.x;
    if (e < E) atomicAdd(&counts[dst[e]], 1);
}

__global__ void scan1_k(const int* __restrict__ counts, int* __restrict__ incl,
                        int* __restrict__ bsums, int n) {
    __shared__ int s[256];
    int i = blockIdx.x * 256 + threadIdx.x;
    int v = (i < n) ? counts[i] : 0;
    s[threadIdx.x] = v;
    __syncthreads();
    for (int off = 1; off < 256; off <<= 1) {
        int t = (threadIdx.x >= off) ? s[threadIdx.x - off] : 0;
        __syncthreads();
        s[threadIdx.x] += t;
        __syncthreads();
    }
    if (i < n) incl[i] = s[threadIdx.x];
    if (threadIdx.x == 255) bsums[blockIdx.x] = s[255];
}

__global__ void scan2_k(const int* __restrict__ bsums, int* __restrict__ boffs, int nb) {
    __shared__ int s[128];
    int tid = threadIdx.x;
    int v = (tid < nb) ? bsums[tid] : 0;
    s[tid] = v;
    __syncthreads();
    for (int off = 1; off < 128; off <<= 1) {
        int t = (tid >= off) ? s[tid - off] : 0;
        __syncthreads();
        s[tid] += t;
        __syncthreads();
    }
    if (tid < nb) boffs[tid] = s[tid] - v;   // exclusive
}

__global__ void scan3_k(const int* __restrict__ incl, const int* __restrict__ counts,
                        const int* __restrict__ boffs, int* __restrict__ row_start,
                        int* __restrict__ cursor, int n) {
    int i = blockIdx.x * 256 + threadIdx.x;
    if (i < n) {
        int st = incl[i] - counts[i] + boffs[blockIdx.x];
        row_start[i] = st;
        cursor[i] = st;
    }
}

__global__ void scatter_k(const int* __restrict__ src, const int* __restrict__ dst,
                          const float* __restrict__ w, int* __restrict__ cursor,
                          int* __restrict__ es, float* __restrict__ ew, int E) {
    int e = blockIdx.x * 256 + threadIdx.x;
    if (e < E) {
        int d = dst[e];
        int p = atomicAdd(&cursor[d], 1);
        es[p] = src[e];
        ew[p] = w[e];
    }
}

// ---------------- LayerNorm: one wave per row, D = 256*VPL ----------------
template <int VPL>
__global__ void ln_k(const float* __restrict__ X, const float* __restrict__ sc,
                     const float* __restrict__ bi, float* __restrict__ Y, int M) {
    const int D = 256 * VPL;
    int row = blockIdx.x * 4 + (threadIdx.x >> 6);
    int lane = threadIdx.x & 63;
    if (row >= M) return;
    const float4* xp = (const float4*)(X + (size_t)row * D);
    float4 v[VPL];
    float sum = 0.f;
#pragma unroll
    for (int i = 0; i < VPL; i++) {
        v[i] = xp[i * 64 + lane];
        sum += v[i].x + v[i].y + v[i].z + v[i].w;
    }
#pragma unroll
    for (int off = 32; off >= 1; off >>= 1) sum += __shfl_xor(sum, off);
    float mu = sum / D;
    float sq = 0.f;
#pragma unroll
    for (int i = 0; i < VPL; i++) {
        float a = v[i].x - mu, b = v[i].y - mu, c = v[i].z - mu, d = v[i].w - mu;
        sq += a * a + b * b + c * c + d * d;
    }
#pragma unroll
    for (int off = 32; off >= 1; off >>= 1) sq += __shfl_xor(sq, off);
    float rstd = rsqrtf(sq / D + 1e-5f);
    float4* yp = (float4*)(Y + (size_t)row * D);
    const float4* sp = (const float4*)sc;
    const float4* bp = (const float4*)bi;
#pragma unroll
    for (int i = 0; i < VPL; i++) {
        float4 s4 = sp[i * 64 + lane], b4 = bp[i * 64 + lane];
        float4 o;
        o.x = (v[i].x - mu) * rstd * s4.x + b4.x;
        o.y = (v[i].y - mu) * rstd * s4.y + b4.y;
        o.z = (v[i].z - mu) * rstd * s4.z + b4.z;
        o.w = (v[i].w - mu) * rstd * s4.w + b4.w;
        yp[i * 64 + lane] = o;
    }
}

// ---------------- CSR aggregation: one wave per dst row ----------------
__global__ void agg_k(const int* __restrict__ row_start, const int* __restrict__ counts,
                      const int* __restrict__ es, const float* __restrict__ ew,
                      const float* __restrict__ H, float* __restrict__ AGG, int n) {
    int row = blockIdx.x * 4 + (threadIdx.x >> 6);
    int lane = threadIdx.x & 63;
    if (row >= n) return;
    int beg = row_start[row], cnt = counts[row];
    float ax = 0.f, ay = 0.f, az = 0.f, aw = 0.f;
    for (int t = 0; t < cnt; t++) {
        int s = es[beg + t];
        float w = ew[beg + t];
        float4 v = *(const float4*)(H + (size_t)s * GDIM + lane * 4);
        ax = fmaf(v.x, w, ax);
        ay = fmaf(v.y, w, ay);
        az = fmaf(v.z, w, az);
        aw = fmaf(v.w, w, aw);
    }
    float4 o = {ax, ay, az, aw};
    *(float4*)(AGG + (size_t)row * GDIM + lane * 4) = o;
}

// ---------------- Generic tiled fp32 GEMM with fused epilogue ----------------
#define TM 64
#define TN 64
#define BKK 32

template <int ACT, bool BT, bool RES, bool BIAS>
__global__ __launch_bounds__(256) void gemm_k(const float* __restrict__ A,
                                              const float* __restrict__ B,
                                              const float* __restrict__ bias,
                                              const float* __restrict__ R,
                                              float* __restrict__ C, int M, int N, int K) {
    __shared__ __align__(16) float As[BKK][TM + 4];
    __shared__ __align__(16) float Bs[BKK][TN + 4];
    int m0 = blockIdx.y * TM;
    int n0 = blockIdx.x * TN;
    int tid = threadIdx.x;
    int tr = tid >> 4;
    int tc = tid & 15;
    float acc[4][4] = {};

    for (int k0 = 0; k0 < K; k0 += BKK) {
        {
            int r = tid >> 3;
            int kq = tid & 7;
#pragma unroll
            for (int p = 0; p < 2; p++) {
                int rr = r + p * 32;
                int gm = m0 + rr;
                float4 v = {0.f, 0.f, 0.f, 0.f};
                if (gm < M) v = *(const float4*)(A + (size_t)gm * K + k0 + kq * 4);
                As[kq * 4 + 0][rr] = v.x;
                As[kq * 4 + 1][rr] = v.y;
                As[kq * 4 + 2][rr] = v.z;
                As[kq * 4 + 3][rr] = v.w;
            }
        }
        if constexpr (!BT) {
            int kk = tid >> 4;
            int c4 = (tid & 15) * 4;
#pragma unroll
            for (int p = 0; p < 2; p++) {
                int kkk = kk + p * 16;
                int gn = n0 + c4;
                float4 v = {0.f, 0.f, 0.f, 0.f};
                if (gn < N) v = *(const float4*)(B + (size_t)(k0 + kkk) * N + gn);
                *(float4*)&Bs[kkk][c4] = v;
            }
        } else {
            int g = tid >> 3;
            int kq = tid & 7;
#pragma unroll
            for (int p = 0; p < 2; p++) {
                int gg = g + p * 32;
                int gn = n0 + gg;
                float4 v = {0.f, 0.f, 0.f, 0.f};
                if (gn < N) v = *(const float4*)(B + (size_t)gn * K + k0 + kq * 4);
                Bs[kq * 4 + 0][gg] = v.x;
                Bs[kq * 4 + 1][gg] = v.y;
                Bs[kq * 4 + 2][gg] = v.z;
                Bs[kq * 4 + 3][gg] = v.w;
            }
        }
        __syncthreads();
#pragma unroll
        for (int kk = 0; kk < BKK; kk++) {
            float4 av = *(const float4*)&As[kk][tr * 4];
            float4 bv = *(const float4*)&Bs[kk][tc * 4];
            acc[0][0] = fmaf(av.x, bv.x, acc[0][0]);
            acc[0][1] = fmaf(av.x, bv.y, acc[0][1]);
            acc[0][2] = fmaf(av.x, bv.z, acc[0][2]);
            acc[0][3] = fmaf(av.x, bv.w, acc[0][3]);
            acc[1][0] = fmaf(av.y, bv.x, acc[1][0]);
            acc[1][1] = fmaf(av.y, bv.y, acc[1][1]);
            acc[1][2] = fmaf(av.y, bv.z, acc[1][2]);
            acc[1][3] = fmaf(av.y, bv.w, acc[1][3]);
            acc[2][0] = fmaf(av.z, bv.x, acc[2][0]);
            acc[2][1] = fmaf(av.z, bv.y, acc[2][1]);
            acc[2][2] = fmaf(av.z, bv.z, acc[2][2]);
            acc[2][3] = fmaf(av.z, bv.w, acc[2][3]);
            acc[3][0] = fmaf(av.w, bv.x, acc[3][0]);
            acc[3][1] = fmaf(av.w, bv.y, acc[3][1]);
            acc[3][2] = fmaf(av.w, bv.z, acc[3][2]);
            acc[3][3] = fmaf(av.w, bv.w, acc[3][3]);
        }
        __syncthreads();
    }

#pragma unroll
    for (int i = 0; i < 4; i++) {
        int gm = m0 + tr * 4 + i;
        if (gm >= M) continue;
#pragma unroll
        for (int j = 0; j < 4; j++) {
            int gn = n0 + tc * 4 + j;
            if (gn >= N) continue;
            float v = acc[i][j];
            if (BIAS) v += bias[gn];
            if (ACT == 1) v = fmaxf(v, 0.f);
            if (ACT == 2) v = 0.5f * v * (1.f + erff(v * 0.70710678118654752f));
            if (RES) v += R[(size_t)gm * N + gn];
            C[(size_t)gm * N + gn] = v;
        }
    }
}

// ---------------- Split-K phase 1: partial GEMM (no epilogue) ----------------
// Cp[s][M][N] = A[:, s*kchunk : (s+1)*kchunk] @ B-chunk.  grid.z = S.
__global__ __launch_bounds__(256) void gemmp_k(const float* __restrict__ A,
                                               const float* __restrict__ B,
                                               float* __restrict__ Cp, int M, int N, int K,
                                               int kchunk) {
    __shared__ __align__(16) float As[BKK][TM + 4];
    __shared__ __align__(16) float Bs[BKK][TN + 4];
    int m0 = blockIdx.y * TM;
    int n0 = blockIdx.x * TN;
    int kbeg = blockIdx.z * kchunk;
    int kend = kbeg + kchunk;
    float* C = Cp + (size_t)blockIdx.z * M * N;
    int tid = threadIdx.x;
    int tr = tid >> 4;
    int tc = tid & 15;
    float acc[4][4] = {};

    for (int k0 = kbeg; k0 < kend; k0 += BKK) {
        {
            int r = tid >> 3;
            int kq = tid & 7;
#pragma unroll
            for (int p = 0; p < 2; p++) {
                int rr = r + p * 32;
                int gm = m0 + rr;
                float4 v = {0.f, 0.f, 0.f, 0.f};
                if (gm < M) v = *(const float4*)(A + (size_t)gm * K + k0 + kq * 4);
                As[kq * 4 + 0][rr] = v.x;
                As[kq * 4 + 1][rr] = v.y;
                As[kq * 4 + 2][rr] = v.z;
                As[kq * 4 + 3][rr] = v.w;
            }
        }
        {
            int kk = tid >> 4;
            int c4 = (tid & 15) * 4;
#pragma unroll
            for (int p = 0; p < 2; p++) {
                int kkk = kk + p * 16;
                int gn = n0 + c4;
                float4 v = {0.f, 0.f, 0.f, 0.f};
                if (gn < N) v = *(const float4*)(B + (size_t)(k0 + kkk) * N + gn);
                *(float4*)&Bs[kkk][c4] = v;
            }
        }
        __syncthreads();
#pragma unroll
        for (int kk = 0; kk < BKK; kk++) {
            float4 av = *(const float4*)&As[kk][tr * 4];
            float4 bv = *(const float4*)&Bs[kk][tc * 4];
            acc[0][0] = fmaf(av.x, bv.x, acc[0][0]);
            acc[0][1] = fmaf(av.x, bv.y, acc[0][1]);
            acc[0][2] = fmaf(av.x, bv.z, acc[0][2]);
            acc[0][3] = fmaf(av.x, bv.w, acc[0][3]);
            acc[1][0] = fmaf(av.y, bv.x, acc[1][0]);
            acc[1][1] = fmaf(av.y, bv.y, acc[1][1]);
            acc[1][2] = fmaf(av.y, bv.z, acc[1][2]);
            acc[1][3] = fmaf(av.y, bv.w, acc[1][3]);
            acc[2][0] = fmaf(av.z, bv.x, acc[2][0]);
            acc[2][1] = fmaf(av.z, bv.y, acc[2][1]);
            acc[2][2] = fmaf(av.z, bv.z, acc[2][2]);
            acc[2][3] = fmaf(av.z, bv.w, acc[2][3]);
            acc[3][0] = fmaf(av.w, bv.x, acc[3][0]);
            acc[3][1] = fmaf(av.w, bv.y, acc[3][1]);
            acc[3][2] = fmaf(av.w, bv.z, acc[3][2]);
            acc[3][3] = fmaf(av.w, bv.w, acc[3][3]);
        }
        __syncthreads();
    }

#pragma unroll
    for (int i = 0; i < 4; i++) {
        int gm = m0 + tr * 4 + i;
#pragma unroll
        for (int j = 0; j < 4; j++) {
            int gn = n0 + tc * 4 + j;
            C[(size_t)gm * N + gn] = acc[i][j];
        }
    }
}

// ---------------- Split-K phase 2: reduce over S + epilogue ----------------
template <int ACT, bool RES, bool BIAS>
__global__ void red_k(const float* __restrict__ Cp, const float* __restrict__ bias,
                      const float* __restrict__ R, float* __restrict__ C, int M, int N, int S) {
    int i = blockIdx.x * 256 + threadIdx.x;   // float4 index
    int MN4 = M * N / 4;
    if (i >= MN4) return;
    float4 a = ((const float4*)Cp)[i];
    for (int s = 1; s < S; s++) {
        float4 b = ((const float4*)Cp)[(size_t)s * MN4 + i];
        a.x += b.x;
        a.y += b.y;
        a.z += b.z;
        a.w += b.w;
    }
    if (BIAS) {
        int n = (i * 4) % N;
        const float4 b4 = *(const float4*)(bias + n);
        a.x += b4.x;
        a.y += b4.y;
        a.z += b4.z;
        a.w += b4.w;
    }
    if (ACT == 1) {
        a.x = fmaxf(a.x, 0.f);
        a.y = fmaxf(a.y, 0.f);
        a.z = fmaxf(a.z, 0.f);
        a.w = fmaxf(a.w, 0.f);
    }
    if (ACT == 2) {
        const float c = 0.70710678118654752f;
        a.x = 0.5f * a.x * (1.f + erff(a.x * c));
        a.y = 0.5f * a.y * (1.f + erff(a.y * c));
        a.z = 0.5f * a.z * (1.f + erff(a.z * c));
        a.w = 0.5f * a.w * (1.f + erff(a.w * c));
    }
    if (RES) {
        float4 r4 = ((const float4*)R)[i];
        a.x += r4.x;
        a.y += r4.y;
        a.z += r4.z;
        a.w += r4.w;
    }
    ((float4*)C)[i] = a;
}

// ---------------- OOV-safe gather / fixup ----------------
__global__ void gather_k(const int* __restrict__ idx, const float* __restrict__ X,
                         float* __restrict__ Y) {
    int b = blockIdx.x;
    int lane = threadIdx.x;
    int id = idx[b];
    int safe = id < 0 ? 0 : id;
    float4 v = *(const float4*)(X + (size_t)safe * GDIM + lane * 4);
    *(float4*)(Y + (size_t)b * GDIM + lane * 4) = v;
}

__global__ void oovfix_k(const int* __restrict__ idx, const float* __restrict__ oov_emb,
                         float* __restrict__ P) {
    int b = blockIdx.x;
    int lane = threadIdx.x;
    if (idx[b] < 0) {
        *(float4*)(P + (size_t)b * GDIM + lane * 4) = ((const float4*)oov_emb)[lane];
    }
}

// ---------------- launch ----------------
extern "C" void kernel_launch(void* const* d_in, const int* in_sizes, int n_in,
                              void* d_out, int out_size, void* d_ws, size_t ws_size,
                              hipStream_t stream) {
    const int* node_indices = (const int*)d_in[0];
    const int* edge_src = (const int*)d_in[1];
    const int* edge_dst = edge_src + NEDGES;
    const float* edge_w = (const float*)d_in[2];
    const float* partial_emb = (const float*)d_in[3];
    const float* oov_emb = (const float*)d_in[4];
    const float* gnn_ln_s = (const float*)d_in[5];
    const float* gnn_ln_b = (const float*)d_in[6];
    const float* gnn_w = (const float*)d_in[7];
    const float* gnn_b = (const float*)d_in[8];
    const float* post_w = (const float*)d_in[9];
    const float* post_b = (const float*)d_in[10];
    const float* pin_w = (const float*)d_in[11];
    const float* pin_b = (const float*)d_in[12];
    const float* blk_ln_s = (const float*)d_in[13];
    const float* blk_ln_b = (const float*)d_in[14];
    const float* blk_w1 = (const float*)d_in[15];
    const float* blk_b1 = (const float*)d_in[16];
    const float* blk_w2 = (const float*)d_in[17];
    const float* blk_b2 = (const float*)d_in[18];
    const float* pout_w = (const float*)d_in[19];
    const float* pout_b = (const float*)d_in[20];
    const float* gene = (const float*)d_in[21];
    float* out = (float*)d_out;

    char* p = (char*)d_ws;
    auto alloc = [&](size_t bytes) {
        char* r = p;
        p += (bytes + 255) & ~(size_t)255;
        return r;
    };
    int* counts = (int*)alloc(NNODES * 4);
    int* incl = (int*)alloc(NNODES * 4);
    int* bsums = (int*)alloc(128 * 4);
    int* boffs = (int*)alloc(128 * 4);
    int* row_start = (int*)alloc(NNODES * 4);
    int* cursor = (int*)alloc(NNODES * 4);
    int* es = (int*)alloc((size_t)NEDGES * 4);
    float* ew = (float*)alloc((size_t)NEDGES * 4);
    float* ln_buf = (float*)alloc((size_t)NNODES * GDIM * 4);
    float* aggb = (float*)alloc((size_t)NNODES * GDIM * 4);   // reused as split-K partials in head
    float* xa = (float*)alloc((size_t)NNODES * GDIM * 4);
    float* xb = (float*)alloc((size_t)NNODES * GDIM * 4);
    float* pert_in = (float*)alloc((size_t)BSZ * GDIM * 4);
    float* pertA = (float*)alloc((size_t)BSZ * GDIM * 4);
    float* hbuf = (float*)alloc((size_t)BSZ * HID * 4);
    float* zln = (float*)alloc((size_t)BSZ * HID * 4);
    float* z1 = (float*)alloc((size_t)BSZ * INNER * 4);
    float* proj = (float*)alloc((size_t)BSZ * NCLS * RANK * 4);

    const int EB = (NEDGES + 255) / 256;
    const int NB = (NNODES + 255) / 256;

    // CSR build
    hipMemsetAsync(counts, 0, NNODES * 4, stream);
    hist_k<<<EB, 256, 0, stream>>>(edge_dst, counts, NEDGES);
    scan1_k<<<NB, 256, 0, stream>>>(counts, incl, bsums, NNODES);
    scan2_k<<<1, 128, 0, stream>>>(bsums, boffs, NB);
    scan3_k<<<NB, 256, 0, stream>>>(incl, counts, boffs, row_start, cursor, NNODES);
    scatter_k<<<EB, 256, 0, stream>>>(edge_src, edge_dst, edge_w, cursor, es, ew, NEDGES);

    // GNN tail: 3 layers (grid already large -> keep fused gemm)
    const float* x_in = partial_emb;
    float* bufs[2] = {xa, xb};
    for (int i = 0; i < 3; i++) {
        ln_k<1><<<(NNODES + 3) / 4, 256, 0, stream>>>(x_in, gnn_ln_s + i * GDIM,
                                                      gnn_ln_b + i * GDIM, ln_buf, NNODES);
        agg_k<<<(NNODES + 3) / 4, 256, 0, stream>>>(row_start, counts, es, ew, ln_buf, aggb,
                                                    NNODES);
        float* x_out = bufs[i & 1];
        gemm_k<1, false, true, true><<<dim3(GDIM / TN, (NNODES + TM - 1) / TM), 256, 0, stream>>>(
            aggb, gnn_w + (size_t)i * GDIM * GDIM, gnn_b + i * GDIM, x_in, x_out, NNODES, GDIM,
            GDIM);
        x_in = x_out;
    }

    float* part = aggb;   // 20.5 MB scratch, free after GNN phase (max need 8 MB)

    // gather + post_mp (split-K S=8) + OOV fixup
    gather_k<<<BSZ, 64, 0, stream>>>(node_indices, x_in, pert_in);
    gemmp_k<<<dim3(GDIM / TN, BSZ / TM, 8), 256, 0, stream>>>(pert_in, post_w, part, BSZ, GDIM,
                                                              GDIM, GDIM / 8);
    red_k<0, false, true><<<(BSZ * GDIM / 4 + 255) / 256, 256, 0, stream>>>(part, post_b, nullptr,
                                                                            pertA, BSZ, GDIM, 8);
    oovfix_k<<<BSZ, 64, 0, stream>>>(node_indices, oov_emb, pertA);

    // pin: [256,256]@[256,512], split-K S=4
    gemmp_k<<<dim3(HID / TN, BSZ / TM, 4), 256, 0, stream>>>(pertA, pin_w, part, BSZ, HID, GDIM,
                                                             GDIM / 4);
    red_k<0, false, true><<<(BSZ * HID / 4 + 255) / 256, 256, 0, stream>>>(part, pin_b, nullptr,
                                                                           hbuf, BSZ, HID, 4);

    // bilinear head blocks
    for (int i = 0; i < 6; i++) {
        ln_k<2><<<BSZ / 4, 256, 0, stream>>>(hbuf, blk_ln_s + i * HID, blk_ln_b + i * HID, zln,
                                             BSZ);
        // w1: [256,512]@[512,2048], S=4 (kchunk 128) -> 512 blocks
        gemmp_k<<<dim3(INNER / TN, BSZ / TM, 4), 256, 0, stream>>>(
            zln, blk_w1 + (size_t)i * HID * INNER, part, BSZ, INNER, HID, HID / 4);
        red_k<2, false, true><<<(BSZ * INNER / 4 + 255) / 256, 256, 0, stream>>>(
            part, blk_b1 + i * INNER, nullptr, z1, BSZ, INNER, 4);
        // w2: [256,2048]@[2048,512], S=16 (kchunk 128) -> 512 blocks
        gemmp_k<<<dim3(HID / TN, BSZ / TM, 16), 256, 0, stream>>>(
            z1, blk_w2 + (size_t)i * INNER * HID, part, BSZ, HID, INNER, INNER / 16);
        red_k<0, true, true><<<(BSZ * HID / 4 + 255) / 256, 256, 0, stream>>>(
            part, blk_b2 + i * HID, hbuf, hbuf, BSZ, HID, 16);
    }

    // pout: [256,512]@[512,1536], S=4 -> 384 blocks
    gemmp_k<<<dim3((NCLS * RANK) / TN, BSZ / TM, 4), 256, 0, stream>>>(hbuf, pout_w, part, BSZ,
                                                                       NCLS * RANK, HID, HID / 4);
    red_k<0, false, true><<<(BSZ * NCLS * RANK / 4 + 255) / 256, 256, 0, stream>>>(
        part, pout_b, nullptr, proj, BSZ, NCLS * RANK, 4);

    // logits: [768,512] @ gene[6640,512]^T  (grid 1248 blocks, keep)
    gemm_k<0, true, false, false><<<dim3((NGENES + TN - 1) / TN, (BSZ * NCLS + TM - 1) / TM), 256,
                                    0, stream>>>(proj, gene, nullptr, nullptr, out, BSZ * NCLS,
                                                 NGENES, RANK);
}

// Round 3
// 906.921 us; speedup vs baseline: 2.1624x; 1.1501x over previous
//
#include <hip/hip_runtime.h>
#include <hip/hip_bf16.h>
#include <math.h>

#define NNODES 20000
#define NEDGES 640000
#define BSZ 256
#define GDIM 256
#define HID 512
#define INNER 2048
#define RANK 512
#define NCLS 3
#define NGENES 6640

typedef __attribute__((ext_vector_type(8))) short bf16x8;
typedef __attribute__((ext_vector_type(4))) float f32x4;

__device__ inline float bf2f(unsigned short u) {
    return __uint_as_float(((unsigned)u) << 16);
}
__device__ inline unsigned short f2bf(float f) {
    unsigned u = __float_as_uint(f);
    u = u + 0x7fff + ((u >> 16) & 1);   // RNE
    return (unsigned short)(u >> 16);
}

// ---------------- CSR build ----------------
__global__ void hist_k(const int* __restrict__ dst, int* __restrict__ counts, int E) {
    int e = blockIdx.x * 256 + threadIdx.x;
    if (e < E) atomicAdd(&counts[dst[e]], 1);
}

__global__ void scan1_k(const int* __restrict__ counts, int* __restrict__ incl,
                        int* __restrict__ bsums, int n) {
    __shared__ int s[256];
    int i = blockIdx.x * 256 + threadIdx.x;
    int v = (i < n) ? counts[i] : 0;
    s[threadIdx.x] = v;
    __syncthreads();
    for (int off = 1; off < 256; off <<= 1) {
        int t = (threadIdx.x >= off) ? s[threadIdx.x - off] : 0;
        __syncthreads();
        s[threadIdx.x] += t;
        __syncthreads();
    }
    if (i < n) incl[i] = s[threadIdx.x];
    if (threadIdx.x == 255) bsums[blockIdx.x] = s[255];
}

__global__ void scan2_k(const int* __restrict__ bsums, int* __restrict__ boffs, int nb) {
    __shared__ int s[128];
    int tid = threadIdx.x;
    int v = (tid < nb) ? bsums[tid] : 0;
    s[tid] = v;
    __syncthreads();
    for (int off = 1; off < 128; off <<= 1) {
        int t = (tid >= off) ? s[tid - off] : 0;
        __syncthreads();
        s[tid] += t;
        __syncthreads();
    }
    if (tid < nb) boffs[tid] = s[tid] - v;
}

__global__ void scan3_k(const int* __restrict__ incl, const int* __restrict__ counts,
                        const int* __restrict__ boffs, int* __restrict__ row_start,
                        int* __restrict__ cursor, int n) {
    int i = blockIdx.x * 256 + threadIdx.x;
    if (i < n) {
        int st = incl[i] - counts[i] + boffs[blockIdx.x];
        row_start[i] = st;
        cursor[i] = st;
    }
}

__global__ void scatter_k(const int* __restrict__ src, const int* __restrict__ dst,
                          const float* __restrict__ w, int* __restrict__ cursor,
                          int* __restrict__ es, float* __restrict__ ew, int E) {
    int e = blockIdx.x * 256 + threadIdx.x;
    if (e < E) {
        int d = dst[e];
        int p = atomicAdd(&cursor[d], 1);
        es[p] = src[e];
        ew[p] = w[e];
    }
}

// ---------------- conversions ----------------
// fp32 -> bf16, 8 elements per thread
__global__ void cvtb_k(const float* __restrict__ X, unsigned short* __restrict__ Y, int n8) {
    int i = blockIdx.x * 256 + threadIdx.x;
    if (i >= n8) return;
    const float4* xp = (const float4*)X;
    float4 a = xp[i * 2], b = xp[i * 2 + 1];
    *(ushort4*)(Y + (size_t)i * 8) = make_ushort4(f2bf(a.x), f2bf(a.y), f2bf(a.z), f2bf(a.w));
    *(ushort4*)(Y + (size_t)i * 8 + 4) = make_ushort4(f2bf(b.x), f2bf(b.y), f2bf(b.z), f2bf(b.w));
}

// W [K][N] fp32 -> WT [N][K] bf16, 32x32 LDS tiles, grid.z = layer
__global__ void tconv_k(const float* __restrict__ W, unsigned short* __restrict__ WT, int K,
                        int N) {
    __shared__ float s[32][33];
    const float* Wl = W + (size_t)blockIdx.z * K * N;
    unsigned short* WTl = WT + (size_t)blockIdx.z * K * N;
    int k0 = blockIdx.y * 32, n0 = blockIdx.x * 32;
#pragma unroll
    for (int i = 0; i < 4; i++)
        s[threadIdx.y + 8 * i][threadIdx.x] = Wl[(size_t)(k0 + threadIdx.y + 8 * i) * N + n0 + threadIdx.x];
    __syncthreads();
#pragma unroll
    for (int i = 0; i < 4; i++)
        WTl[(size_t)(n0 + threadIdx.y + 8 * i) * K + k0 + threadIdx.x] =
            f2bf(s[threadIdx.x][threadIdx.y + 8 * i]);
}

// ---------------- LayerNorm ----------------
// fp32 out (head), D = 256*VPL
template <int VPL>
__global__ void ln_k(const float* __restrict__ X, const float* __restrict__ sc,
                     const float* __restrict__ bi, float* __restrict__ Y, int M) {
    const int D = 256 * VPL;
    int row = blockIdx.x * 4 + (threadIdx.x >> 6);
    int lane = threadIdx.x & 63;
    if (row >= M) return;
    const float4* xp = (const float4*)(X + (size_t)row * D);
    float4 v[VPL];
    float sum = 0.f;
#pragma unroll
    for (int i = 0; i < VPL; i++) {
        v[i] = xp[i * 64 + lane];
        sum += v[i].x + v[i].y + v[i].z + v[i].w;
    }
#pragma unroll
    for (int off = 32; off >= 1; off >>= 1) sum += __shfl_xor(sum, off);
    float mu = sum / D;
    float sq = 0.f;
#pragma unroll
    for (int i = 0; i < VPL; i++) {
        float a = v[i].x - mu, b = v[i].y - mu, c = v[i].z - mu, d = v[i].w - mu;
        sq += a * a + b * b + c * c + d * d;
    }
#pragma unroll
    for (int off = 32; off >= 1; off >>= 1) sq += __shfl_xor(sq, off);
    float rstd = rsqrtf(sq / D + 1e-5f);
    float4* yp = (float4*)(Y + (size_t)row * D);
    const float4* sp = (const float4*)sc;
    const float4* bp = (const float4*)bi;
#pragma unroll
    for (int i = 0; i < VPL; i++) {
        float4 s4 = sp[i * 64 + lane], b4 = bp[i * 64 + lane];
        float4 o;
        o.x = (v[i].x - mu) * rstd * s4.x + b4.x;
        o.y = (v[i].y - mu) * rstd * s4.y + b4.y;
        o.z = (v[i].z - mu) * rstd * s4.z + b4.z;
        o.w = (v[i].w - mu) * rstd * s4.w + b4.w;
        yp[i * 64 + lane] = o;
    }
}

// bf16 out, D = 256 (GNN)
__global__ void lnb_k(const float* __restrict__ X, const float* __restrict__ sc,
                      const float* __restrict__ bi, unsigned short* __restrict__ Y, int M) {
    int row = blockIdx.x * 4 + (threadIdx.x >> 6);
    int lane = threadIdx.x & 63;
    if (row >= M) return;
    float4 v = ((const float4*)(X + (size_t)row * GDIM))[lane];
    float sum = v.x + v.y + v.z + v.w;
#pragma unroll
    for (int off = 32; off >= 1; off >>= 1) sum += __shfl_xor(sum, off);
    float mu = sum / GDIM;
    float a = v.x - mu, b = v.y - mu, c = v.z - mu, d = v.w - mu;
    float sq = a * a + b * b + c * c + d * d;
#pragma unroll
    for (int off = 32; off >= 1; off >>= 1) sq += __shfl_xor(sq, off);
    float rstd = rsqrtf(sq / GDIM + 1e-5f);
    float4 s4 = ((const float4*)sc)[lane];
    float4 b4 = ((const float4*)bi)[lane];
    *(ushort4*)(Y + (size_t)row * GDIM + lane * 4) =
        make_ushort4(f2bf(a * rstd * s4.x + b4.x), f2bf(b * rstd * s4.y + b4.y),
                     f2bf(c * rstd * s4.z + b4.z), f2bf(d * rstd * s4.w + b4.w));
}

// ---------------- CSR aggregation over bf16 rows, bf16 out ----------------
__global__ void aggb_k(const int* __restrict__ row_start, const int* __restrict__ counts,
                       const int* __restrict__ es, const float* __restrict__ ew,
                       const unsigned short* __restrict__ H, unsigned short* __restrict__ AGG,
                       int n) {
    int row = blockIdx.x * 4 + (threadIdx.x >> 6);
    int lane = threadIdx.x & 63;
    if (row >= n) return;
    int beg = row_start[row], cnt = counts[row];
    float a0 = 0.f, a1 = 0.f, a2 = 0.f, a3 = 0.f;
    for (int t = 0; t < cnt; t++) {
        int s = es[beg + t];
        float w = ew[beg + t];
        ushort4 v = *(const ushort4*)(H + (size_t)s * GDIM + lane * 4);
        a0 = fmaf(bf2f(v.x), w, a0);
        a1 = fmaf(bf2f(v.y), w, a1);
        a2 = fmaf(bf2f(v.z), w, a2);
        a3 = fmaf(bf2f(v.w), w, a3);
    }
    *(ushort4*)(AGG + (size_t)row * GDIM + lane * 4) =
        make_ushort4(f2bf(a0), f2bf(a1), f2bf(a2), f2bf(a3));
}

// ---------------- bf16 MFMA GEMM: C[M,N] = epi(A @ B), BT = [N][K] bf16 ----------------
// 128x128 tile, BK=32, 4 waves in 2x2, each wave 64x64 (4x4 of 16x16x32 MFMA).
// ACT: 0 none, 1 relu.  RES: += R[m][n].  BIAS: += bias[n].  C fp32.
template <int ACT, bool RES, bool BIAS>
__global__ __launch_bounds__(256) void mgemm_k(const unsigned short* __restrict__ A,
                                               const unsigned short* __restrict__ BT,
                                               const float* __restrict__ bias,
                                               const float* __restrict__ R,
                                               float* __restrict__ C, int M, int N, int K) {
    __shared__ unsigned short As[128 * 32];
    __shared__ unsigned short Bs[128 * 32];
    int m0 = blockIdx.y * 128, n0 = blockIdx.x * 128;
    int tid = threadIdx.x;
    int wave = tid >> 6, lane = tid & 63;
    int wm = (wave >> 1) * 64, wn = (wave & 1) * 64;
    int lrow = lane & 15, lq = lane >> 4;

    f32x4 acc[4][4];
    const f32x4 zz = {0.f, 0.f, 0.f, 0.f};
#pragma unroll
    for (int i = 0; i < 4; i++)
#pragma unroll
        for (int j = 0; j < 4; j++) acc[i][j] = zz;

    int r0 = tid >> 2;   // 0..63
    int q = tid & 3;     // 16B quarter of a 64B row

    for (int k0 = 0; k0 < K; k0 += 32) {
#pragma unroll
        for (int p = 0; p < 2; p++) {
            int row = r0 + p * 64;
            int gm = m0 + row;
            uint4 va = make_uint4(0, 0, 0, 0);
            if (gm < M) va = *(const uint4*)(A + (size_t)gm * K + k0 + q * 8);
            *(uint4*)&As[row * 32 + q * 8] = va;
            int gn = n0 + row;
            uint4 vb = make_uint4(0, 0, 0, 0);
            if (gn < N) vb = *(const uint4*)(BT + (size_t)gn * K + k0 + q * 8);
            *(uint4*)&Bs[row * 32 + q * 8] = vb;
        }
        __syncthreads();
        bf16x8 af[4], bf[4];
#pragma unroll
        for (int i = 0; i < 4; i++)
            af[i] = *(const bf16x8*)&As[(wm + i * 16 + lrow) * 32 + lq * 8];
#pragma unroll
        for (int j = 0; j < 4; j++)
            bf[j] = *(const bf16x8*)&Bs[(wn + j * 16 + lrow) * 32 + lq * 8];
#pragma unroll
        for (int i = 0; i < 4; i++)
#pragma unroll
            for (int j = 0; j < 4; j++)
                acc[i][j] = __builtin_amdgcn_mfma_f32_16x16x32_bf16(af[i], bf[j], acc[i][j], 0, 0, 0);
        __syncthreads();
    }

    // epilogue: C/D layout col = lane&15, row = (lane>>4)*4 + reg
#pragma unroll
    for (int i = 0; i < 4; i++) {
#pragma unroll
        for (int j = 0; j < 4; j++) {
            int gn = n0 + wn + j * 16 + lrow;
            if (gn >= N) continue;
            float bv = BIAS ? bias[gn] : 0.f;
#pragma unroll
            for (int r = 0; r < 4; r++) {
                int gm = m0 + wm + i * 16 + lq * 4 + r;
                if (gm >= M) continue;
                float v = acc[i][j][r] + bv;
                if (ACT == 1) v = fmaxf(v, 0.f);
                if (RES) v += R[(size_t)gm * N + gn];
                C[(size_t)gm * N + gn] = v;
            }
        }
    }
}

// ---------------- fp32 split-K GEMM (head) ----------------
#define TM 64
#define TN 64
#define BKK 32

__global__ __launch_bounds__(256) void gemmp_k(const float* __restrict__ A,
                                               const float* __restrict__ B,
                                               float* __restrict__ Cp, int M, int N, int K,
                                               int kchunk) {
    __shared__ __align__(16) float As[BKK][TM + 4];
    __shared__ __align__(16) float Bs[BKK][TN + 4];
    int m0 = blockIdx.y * TM;
    int n0 = blockIdx.x * TN;
    int kbeg = blockIdx.z * kchunk;
    int kend = kbeg + kchunk;
    float* C = Cp + (size_t)blockIdx.z * M * N;
    int tid = threadIdx.x;
    int tr = tid >> 4;
    int tc = tid & 15;
    float acc[4][4] = {};

    for (int k0 = kbeg; k0 < kend; k0 += BKK) {
        {
            int r = tid >> 3;
            int kq = tid & 7;
#pragma unroll
            for (int p = 0; p < 2; p++) {
                int rr = r + p * 32;
                int gm = m0 + rr;
                float4 v = {0.f, 0.f, 0.f, 0.f};
                if (gm < M) v = *(const float4*)(A + (size_t)gm * K + k0 + kq * 4);
                As[kq * 4 + 0][rr] = v.x;
                As[kq * 4 + 1][rr] = v.y;
                As[kq * 4 + 2][rr] = v.z;
                As[kq * 4 + 3][rr] = v.w;
            }
        }
        {
            int kk = tid >> 4;
            int c4 = (tid & 15) * 4;
#pragma unroll
            for (int p = 0; p < 2; p++) {
                int kkk = kk + p * 16;
                int gn = n0 + c4;
                float4 v = {0.f, 0.f, 0.f, 0.f};
                if (gn < N) v = *(const float4*)(B + (size_t)(k0 + kkk) * N + gn);
                *(float4*)&Bs[kkk][c4] = v;
            }
        }
        __syncthreads();
#pragma unroll
        for (int kk = 0; kk < BKK; kk++) {
            float4 av = *(const float4*)&As[kk][tr * 4];
            float4 bv = *(const float4*)&Bs[kk][tc * 4];
            acc[0][0] = fmaf(av.x, bv.x, acc[0][0]);
            acc[0][1] = fmaf(av.x, bv.y, acc[0][1]);
            acc[0][2] = fmaf(av.x, bv.z, acc[0][2]);
            acc[0][3] = fmaf(av.x, bv.w, acc[0][3]);
            acc[1][0] = fmaf(av.y, bv.x, acc[1][0]);
            acc[1][1] = fmaf(av.y, bv.y, acc[1][1]);
            acc[1][2] = fmaf(av.y, bv.z, acc[1][2]);
            acc[1][3] = fmaf(av.y, bv.w, acc[1][3]);
            acc[2][0] = fmaf(av.z, bv.x, acc[2][0]);
            acc[2][1] = fmaf(av.z, bv.y, acc[2][1]);
            acc[2][2] = fmaf(av.z, bv.z, acc[2][2]);
            acc[2][3] = fmaf(av.z, bv.w, acc[2][3]);
            acc[3][0] = fmaf(av.w, bv.x, acc[3][0]);
            acc[3][1] = fmaf(av.w, bv.y, acc[3][1]);
            acc[3][2] = fmaf(av.w, bv.z, acc[3][2]);
            acc[3][3] = fmaf(av.w, bv.w, acc[3][3]);
        }
        __syncthreads();
    }

#pragma unroll
    for (int i = 0; i < 4; i++) {
        int gm = m0 + tr * 4 + i;
#pragma unroll
        for (int j = 0; j < 4; j++) {
            int gn = n0 + tc * 4 + j;
            C[(size_t)gm * N + gn] = acc[i][j];
        }
    }
}

template <int ACT, bool RES, bool BIAS>
__global__ void red_k(const float* __restrict__ Cp, const float* __restrict__ bias,
                      const float* __restrict__ R, float* __restrict__ C, int M, int N, int S) {
    int i = blockIdx.x * 256 + threadIdx.x;
    int MN4 = M * N / 4;
    if (i >= MN4) return;
    float4 a = ((const float4*)Cp)[i];
    for (int s = 1; s < S; s++) {
        float4 b = ((const float4*)Cp)[(size_t)s * MN4 + i];
        a.x += b.x;
        a.y += b.y;
        a.z += b.z;
        a.w += b.w;
    }
    if (BIAS) {
        int n = (i * 4) % N;
        const float4 b4 = *(const float4*)(bias + n);
        a.x += b4.x;
        a.y += b4.y;
        a.z += b4.z;
        a.w += b4.w;
    }
    if (ACT == 1) {
        a.x = fmaxf(a.x, 0.f);
        a.y = fmaxf(a.y, 0.f);
        a.z = fmaxf(a.z, 0.f);
        a.w = fmaxf(a.w, 0.f);
    }
    if (ACT == 2) {
        const float c = 0.70710678118654752f;
        a.x = 0.5f * a.x * (1.f + erff(a.x * c));
        a.y = 0.5f * a.y * (1.f + erff(a.y * c));
        a.z = 0.5f * a.z * (1.f + erff(a.z * c));
        a.w = 0.5f * a.w * (1.f + erff(a.w * c));
    }
    if (RES) {
        float4 r4 = ((const float4*)R)[i];
        a.x += r4.x;
        a.y += r4.y;
        a.z += r4.z;
        a.w += r4.w;
    }
    ((float4*)C)[i] = a;
}

// ---------------- OOV-safe gather / fixup ----------------
__global__ void gather_k(const int* __restrict__ idx, const float* __restrict__ X,
                         float* __restrict__ Y) {
    int b = blockIdx.x;
    int lane = threadIdx.x;
    int id = idx[b];
    int safe = id < 0 ? 0 : id;
    float4 v = *(const float4*)(X + (size_t)safe * GDIM + lane * 4);
    *(float4*)(Y + (size_t)b * GDIM + lane * 4) = v;
}

__global__ void oovfix_k(const int* __restrict__ idx, const float* __restrict__ oov_emb,
                         float* __restrict__ P) {
    int b = blockIdx.x;
    int lane = threadIdx.x;
    if (idx[b] < 0) {
        *(float4*)(P + (size_t)b * GDIM + lane * 4) = ((const float4*)oov_emb)[lane];
    }
}

// ---------------- launch ----------------
extern "C" void kernel_launch(void* const* d_in, const int* in_sizes, int n_in,
                              void* d_out, int out_size, void* d_ws, size_t ws_size,
                              hipStream_t stream) {
    const int* node_indices = (const int*)d_in[0];
    const int* edge_src = (const int*)d_in[1];
    const int* edge_dst = edge_src + NEDGES;
    const float* edge_w = (const float*)d_in[2];
    const float* partial_emb = (const float*)d_in[3];
    const float* oov_emb = (const float*)d_in[4];
    const float* gnn_ln_s = (const float*)d_in[5];
    const float* gnn_ln_b = (const float*)d_in[6];
    const float* gnn_w = (const float*)d_in[7];
    const float* gnn_b = (const float*)d_in[8];
    const float* post_w = (const float*)d_in[9];
    const float* post_b = (const float*)d_in[10];
    const float* pin_w = (const float*)d_in[11];
    const float* pin_b = (const float*)d_in[12];
    const float* blk_ln_s = (const float*)d_in[13];
    const float* blk_ln_b = (const float*)d_in[14];
    const float* blk_w1 = (const float*)d_in[15];
    const float* blk_b1 = (const float*)d_in[16];
    const float* blk_w2 = (const float*)d_in[17];
    const float* blk_b2 = (const float*)d_in[18];
    const float* pout_w = (const float*)d_in[19];
    const float* pout_b = (const float*)d_in[20];
    const float* gene = (const float*)d_in[21];
    float* out = (float*)d_out;

    char* p = (char*)d_ws;
    auto alloc = [&](size_t bytes) {
        char* r = p;
        p += (bytes + 255) & ~(size_t)255;
        return r;
    };
    int* counts = (int*)alloc(NNODES * 4);
    int* incl = (int*)alloc(NNODES * 4);
    int* bsums = (int*)alloc(128 * 4);
    int* boffs = (int*)alloc(128 * 4);
    int* row_start = (int*)alloc(NNODES * 4);
    int* cursor = (int*)alloc(NNODES * 4);
    int* es = (int*)alloc((size_t)NEDGES * 4);
    float* ew = (float*)alloc((size_t)NEDGES * 4);
    float* part = (float*)alloc((size_t)NNODES * GDIM * 4);  // GNN: ln_bf+aggbf; head: split-K scratch
    unsigned short* ln_bf = (unsigned short*)part;                              // 10.25 MB
    unsigned short* aggbf = (unsigned short*)((char*)part + (size_t)NNODES * GDIM * 2);  // 10.25 MB
    float* xa = (float*)alloc((size_t)NNODES * GDIM * 4);
    float* xb = (float*)alloc((size_t)NNODES * GDIM * 4);
    float* pert_in = (float*)alloc((size_t)BSZ * GDIM * 4);
    float* pertA = (float*)alloc((size_t)BSZ * GDIM * 4);
    float* hbuf = (float*)alloc((size_t)BSZ * HID * 4);
    float* zln = (float*)alloc((size_t)BSZ * HID * 4);
    float* z1 = (float*)alloc((size_t)BSZ * INNER * 4);
    float* proj = (float*)alloc((size_t)BSZ * NCLS * RANK * 4);
    unsigned short* wbt = (unsigned short*)alloc((size_t)3 * GDIM * GDIM * 2);
    unsigned short* geneb = (unsigned short*)alloc((size_t)NGENES * RANK * 2);
    unsigned short* projb = (unsigned short*)alloc((size_t)BSZ * NCLS * RANK * 2);

    const int EB = (NEDGES + 255) / 256;
    const int NB = (NNODES + 255) / 256;

    // weight conversions (per launch; inputs restored every call)
    tconv_k<<<dim3(GDIM / 32, GDIM / 32, 3), dim3(32, 8), 0, stream>>>(gnn_w, wbt, GDIM, GDIM);
    cvtb_k<<<(NGENES * RANK / 8 + 255) / 256, 256, 0, stream>>>(gene, geneb, NGENES * RANK / 8);

    // CSR build
    hipMemsetAsync(counts, 0, NNODES * 4, stream);
    hist_k<<<EB, 256, 0, stream>>>(edge_dst, counts, NEDGES);
    scan1_k<<<NB, 256, 0, stream>>>(counts, incl, bsums, NNODES);
    scan2_k<<<1, 128, 0, stream>>>(bsums, boffs, NB);
    scan3_k<<<NB, 256, 0, stream>>>(incl, counts, boffs, row_start, cursor, NNODES);
    scatter_k<<<EB, 256, 0, stream>>>(edge_src, edge_dst, edge_w, cursor, es, ew, NEDGES);

    // GNN tail: 3 layers, bf16 LN/gather/MFMA, fp32 residual stream
    const float* x_in = partial_emb;
    float* bufs[2] = {xa, xb};
    for (int i = 0; i < 3; i++) {
        lnb_k<<<(NNODES + 3) / 4, 256, 0, stream>>>(x_in, gnn_ln_s + i * GDIM,
                                                    gnn_ln_b + i * GDIM, ln_bf, NNODES);
        aggb_k<<<(NNODES + 3) / 4, 256, 0, stream>>>(row_start, counts, es, ew, ln_bf, aggbf,
                                                     NNODES);
        float* x_out = bufs[i & 1];
        mgemm_k<1, true, true><<<dim3(GDIM / 128, (NNODES + 127) / 128), 256, 0, stream>>>(
            aggbf, wbt + (size_t)i * GDIM * GDIM, gnn_b + i * GDIM, x_in, x_out, NNODES, GDIM,
            GDIM);
        x_in = x_out;
    }

    // gather + post_mp (split-K) + OOV fixup
    gather_k<<<BSZ, 64, 0, stream>>>(node_indices, x_in, pert_in);
    gemmp_k<<<dim3(GDIM / TN, BSZ / TM, 8), 256, 0, stream>>>(pert_in, post_w, part, BSZ, GDIM,
                                                              GDIM, GDIM / 8);
    red_k<0, false, true><<<(BSZ * GDIM / 4 + 255) / 256, 256, 0, stream>>>(part, post_b, nullptr,
                                                                            pertA, BSZ, GDIM, 8);
    oovfix_k<<<BSZ, 64, 0, stream>>>(node_indices, oov_emb, pertA);

    // pin
    gemmp_k<<<dim3(HID / TN, BSZ / TM, 4), 256, 0, stream>>>(pertA, pin_w, part, BSZ, HID, GDIM,
                                                             GDIM / 4);
    red_k<0, false, true><<<(BSZ * HID / 4 + 255) / 256, 256, 0, stream>>>(part, pin_b, nullptr,
                                                                           hbuf, BSZ, HID, 4);

    // bilinear head blocks
    for (int i = 0; i < 6; i++) {
        ln_k<2><<<BSZ / 4, 256, 0, stream>>>(hbuf, blk_ln_s + i * HID, blk_ln_b + i * HID, zln,
                                             BSZ);
        gemmp_k<<<dim3(INNER / TN, BSZ / TM, 4), 256, 0, stream>>>(
            zln, blk_w1 + (size_t)i * HID * INNER, part, BSZ, INNER, HID, HID / 4);
        red_k<2, false, true><<<(BSZ * INNER / 4 + 255) / 256, 256, 0, stream>>>(
            part, blk_b1 + i * INNER, nullptr, z1, BSZ, INNER, 4);
        gemmp_k<<<dim3(HID / TN, BSZ / TM, 16), 256, 0, stream>>>(
            z1, blk_w2 + (size_t)i * INNER * HID, part, BSZ, HID, INNER, INNER / 16);
        red_k<0, true, true><<<(BSZ * HID / 4 + 255) / 256, 256, 0, stream>>>(
            part, blk_b2 + i * HID, hbuf, hbuf, BSZ, HID, 16);
    }

    // pout
    gemmp_k<<<dim3((NCLS * RANK) / TN, BSZ / TM, 4), 256, 0, stream>>>(hbuf, pout_w, part, BSZ,
                                                                       NCLS * RANK, HID, HID / 4);
    red_k<0, false, true><<<(BSZ * NCLS * RANK / 4 + 255) / 256, 256, 0, stream>>>(
        part, pout_b, nullptr, proj, BSZ, NCLS * RANK, 4);

    // logits via bf16 MFMA: proj -> bf16, gene already [N][K] bf16
    cvtb_k<<<(BSZ * NCLS * RANK / 8 + 255) / 256, 256, 0, stream>>>(proj, projb,
                                                                    BSZ * NCLS * RANK / 8);
    mgemm_k<0, false, false><<<dim3((NGENES + 127) / 128, (BSZ * NCLS) / 128), 256, 0, stream>>>(
        projb, geneb, nullptr, nullptr, out, BSZ * NCLS, NGENES, RANK);
}

// Round 4
// 677.917 us; speedup vs baseline: 2.8929x; 1.3378x over previous
//
#include <hip/hip_runtime.h>
#include <hip/hip_bf16.h>
#include <math.h>

#define NNODES 20000
#define NEDGES 640000
#define BSZ 256
#define GDIM 256
#define HID 512
#define INNER 2048
#define RANK 512
#define NCLS 3
#define NGENES 6640

typedef __attribute__((ext_vector_type(8))) short bf16x8;
typedef __attribute__((ext_vector_type(4))) float f32x4;

__device__ inline float bf2f(unsigned short u) {
    return __uint_as_float(((unsigned)u) << 16);
}
__device__ inline unsigned short f2bf(float f) {
    unsigned u = __float_as_uint(f);
    u = u + 0x7fff + ((u >> 16) & 1);   // RNE
    return (unsigned short)(u >> 16);
}

// ---------------- CSR build ----------------
__global__ void hist_k(const int* __restrict__ dst, int* __restrict__ counts, int E) {
    int e = blockIdx.x * 256 + threadIdx.x;
    if (e < E) atomicAdd(&counts[dst[e]], 1);
}

__global__ void scan1_k(const int* __restrict__ counts, int* __restrict__ incl,
                        int* __restrict__ bsums, int n) {
    __shared__ int s[256];
    int i = blockIdx.x * 256 + threadIdx.x;
    int v = (i < n) ? counts[i] : 0;
    s[threadIdx.x] = v;
    __syncthreads();
    for (int off = 1; off < 256; off <<= 1) {
        int t = (threadIdx.x >= off) ? s[threadIdx.x - off] : 0;
        __syncthreads();
        s[threadIdx.x] += t;
        __syncthreads();
    }
    if (i < n) incl[i] = s[threadIdx.x];
    if (threadIdx.x == 255) bsums[blockIdx.x] = s[255];
}

__global__ void scan2_k(const int* __restrict__ bsums, int* __restrict__ boffs, int nb) {
    __shared__ int s[128];
    int tid = threadIdx.x;
    int v = (tid < nb) ? bsums[tid] : 0;
    s[tid] = v;
    __syncthreads();
    for (int off = 1; off < 128; off <<= 1) {
        int t = (tid >= off) ? s[tid - off] : 0;
        __syncthreads();
        s[tid] += t;
        __syncthreads();
    }
    if (tid < nb) boffs[tid] = s[tid] - v;
}

__global__ void scan3_k(const int* __restrict__ incl, const int* __restrict__ counts,
                        const int* __restrict__ boffs, int* __restrict__ row_start,
                        int* __restrict__ cursor, int n) {
    int i = blockIdx.x * 256 + threadIdx.x;
    if (i < n) {
        int st = incl[i] - counts[i] + boffs[blockIdx.x];
        row_start[i] = st;
        cursor[i] = st;
    }
}

// edges packed as (src, weight-bits) int2 for single-load access
__global__ void scatter_k(const int* __restrict__ src, const int* __restrict__ dst,
                          const float* __restrict__ w, int* __restrict__ cursor,
                          int2* __restrict__ ep, int E) {
    int e = blockIdx.x * 256 + threadIdx.x;
    if (e < E) {
        int d = dst[e];
        int p = atomicAdd(&cursor[d], 1);
        ep[p] = make_int2(src[e], __float_as_int(w[e]));
    }
}

// ---------------- conversions ----------------
__global__ void cvtb_k(const float* __restrict__ X, unsigned short* __restrict__ Y, int n8) {
    int i = blockIdx.x * 256 + threadIdx.x;
    if (i >= n8) return;
    const float4* xp = (const float4*)X;
    float4 a = xp[i * 2], b = xp[i * 2 + 1];
    *(ushort4*)(Y + (size_t)i * 8) = make_ushort4(f2bf(a.x), f2bf(a.y), f2bf(a.z), f2bf(a.w));
    *(ushort4*)(Y + (size_t)i * 8 + 4) = make_ushort4(f2bf(b.x), f2bf(b.y), f2bf(b.z), f2bf(b.w));
}

// W [K][N] fp32 -> WT [N][K] bf16, 32x32 LDS tiles, grid.z = layer
__global__ void tconv_k(const float* __restrict__ W, unsigned short* __restrict__ WT, int K,
                        int N) {
    __shared__ float s[32][33];
    const float* Wl = W + (size_t)blockIdx.z * K * N;
    unsigned short* WTl = WT + (size_t)blockIdx.z * K * N;
    int k0 = blockIdx.y * 32, n0 = blockIdx.x * 32;
#pragma unroll
    for (int i = 0; i < 4; i++)
        s[threadIdx.y + 8 * i][threadIdx.x] =
            Wl[(size_t)(k0 + threadIdx.y + 8 * i) * N + n0 + threadIdx.x];
    __syncthreads();
#pragma unroll
    for (int i = 0; i < 4; i++)
        WTl[(size_t)(n0 + threadIdx.y + 8 * i) * K + k0 + threadIdx.x] =
            f2bf(s[threadIdx.x][threadIdx.y + 8 * i]);
}

// ---------------- GNN LayerNorm (D=256), bf16 out ----------------
__global__ void lnb_k(const float* __restrict__ X, const float* __restrict__ sc,
                      const float* __restrict__ bi, unsigned short* __restrict__ Y, int M) {
    int row = blockIdx.x * 4 + (threadIdx.x >> 6);
    int lane = threadIdx.x & 63;
    if (row >= M) return;
    float4 v = ((const float4*)(X + (size_t)row * GDIM))[lane];
    float sum = v.x + v.y + v.z + v.w;
#pragma unroll
    for (int off = 32; off >= 1; off >>= 1) sum += __shfl_xor(sum, off);
    float mu = sum / GDIM;
    float a = v.x - mu, b = v.y - mu, c = v.z - mu, d = v.w - mu;
    float sq = a * a + b * b + c * c + d * d;
#pragma unroll
    for (int off = 32; off >= 1; off >>= 1) sq += __shfl_xor(sq, off);
    float rstd = rsqrtf(sq / GDIM + 1e-5f);
    float4 s4 = ((const float4*)sc)[lane];
    float4 b4 = ((const float4*)bi)[lane];
    *(ushort4*)(Y + (size_t)row * GDIM + lane * 4) =
        make_ushort4(f2bf(a * rstd * s4.x + b4.x), f2bf(b * rstd * s4.y + b4.y),
                     f2bf(c * rstd * s4.z + b4.z), f2bf(d * rstd * s4.w + b4.w));
}

// ---------------- CSR aggregation, 8-deep MLP unroll ----------------
__global__ void aggb_k(const int* __restrict__ row_start, const int* __restrict__ counts,
                       const int2* __restrict__ ep, const unsigned short* __restrict__ H,
                       unsigned short* __restrict__ AGG, int n) {
    int row = blockIdx.x * 4 + (threadIdx.x >> 6);
    int lane = threadIdx.x & 63;
    if (row >= n) return;
    int beg = row_start[row], cnt = counts[row];
    float a0 = 0.f, a1 = 0.f, a2 = 0.f, a3 = 0.f;
    int t = 0;
    for (; t + 8 <= cnt; t += 8) {
        int2 e[8];
#pragma unroll
        for (int u = 0; u < 8; u++) e[u] = ep[beg + t + u];
        ushort4 v[8];
#pragma unroll
        for (int u = 0; u < 8; u++)
            v[u] = *(const ushort4*)(H + (size_t)e[u].x * GDIM + lane * 4);
#pragma unroll
        for (int u = 0; u < 8; u++) {
            float w = __int_as_float(e[u].y);
            a0 = fmaf(bf2f(v[u].x), w, a0);
            a1 = fmaf(bf2f(v[u].y), w, a1);
            a2 = fmaf(bf2f(v[u].z), w, a2);
            a3 = fmaf(bf2f(v[u].w), w, a3);
        }
    }
    for (; t < cnt; t++) {
        int2 e = ep[beg + t];
        float w = __int_as_float(e.y);
        ushort4 v = *(const ushort4*)(H + (size_t)e.x * GDIM + lane * 4);
        a0 = fmaf(bf2f(v.x), w, a0);
        a1 = fmaf(bf2f(v.y), w, a1);
        a2 = fmaf(bf2f(v.z), w, a2);
        a3 = fmaf(bf2f(v.w), w, a3);
    }
    *(ushort4*)(AGG + (size_t)row * GDIM + lane * 4) =
        make_ushort4(f2bf(a0), f2bf(a1), f2bf(a2), f2bf(a3));
}

// ---------------- bf16 MFMA GEMM (full-K, fused epilogue) — GNN layers & logits ----------------
// 128x128 tile, 4 waves 2x2, each 64x64. BT = [N][K] bf16. C fp32.
template <int ACT, bool RES, bool BIAS>
__global__ __launch_bounds__(256) void mgemm_k(const unsigned short* __restrict__ A,
                                               const unsigned short* __restrict__ BT,
                                               const float* __restrict__ bias,
                                               const float* __restrict__ R,
                                               float* __restrict__ C, int M, int N, int K) {
    __shared__ unsigned short As[128 * 32];
    __shared__ unsigned short Bs[128 * 32];
    int m0 = blockIdx.y * 128, n0 = blockIdx.x * 128;
    int tid = threadIdx.x;
    int wave = tid >> 6, lane = tid & 63;
    int wm = (wave >> 1) * 64, wn = (wave & 1) * 64;
    int lrow = lane & 15, lq = lane >> 4;

    f32x4 acc[4][4];
    const f32x4 zz = {0.f, 0.f, 0.f, 0.f};
#pragma unroll
    for (int i = 0; i < 4; i++)
#pragma unroll
        for (int j = 0; j < 4; j++) acc[i][j] = zz;

    int r0 = tid >> 2;
    int q = tid & 3;

    for (int k0 = 0; k0 < K; k0 += 32) {
#pragma unroll
        for (int p = 0; p < 2; p++) {
            int row = r0 + p * 64;
            int gm = m0 + row;
            uint4 va = make_uint4(0, 0, 0, 0);
            if (gm < M) va = *(const uint4*)(A + (size_t)gm * K + k0 + q * 8);
            *(uint4*)&As[row * 32 + q * 8] = va;
            int gn = n0 + row;
            uint4 vb = make_uint4(0, 0, 0, 0);
            if (gn < N) vb = *(const uint4*)(BT + (size_t)gn * K + k0 + q * 8);
            *(uint4*)&Bs[row * 32 + q * 8] = vb;
        }
        __syncthreads();
        bf16x8 af[4], bf[4];
#pragma unroll
        for (int i = 0; i < 4; i++)
            af[i] = *(const bf16x8*)&As[(wm + i * 16 + lrow) * 32 + lq * 8];
#pragma unroll
        for (int j = 0; j < 4; j++)
            bf[j] = *(const bf16x8*)&Bs[(wn + j * 16 + lrow) * 32 + lq * 8];
#pragma unroll
        for (int i = 0; i < 4; i++)
#pragma unroll
            for (int j = 0; j < 4; j++)
                acc[i][j] =
                    __builtin_amdgcn_mfma_f32_16x16x32_bf16(af[i], bf[j], acc[i][j], 0, 0, 0);
        __syncthreads();
    }

#pragma unroll
    for (int i = 0; i < 4; i++) {
#pragma unroll
        for (int j = 0; j < 4; j++) {
            int gn = n0 + wn + j * 16 + lrow;
            if (gn >= N) continue;
            float bv = BIAS ? bias[gn] : 0.f;
#pragma unroll
            for (int r = 0; r < 4; r++) {
                int gm = m0 + wm + i * 16 + lq * 4 + r;
                if (gm >= M) continue;
                float v = acc[i][j][r] + bv;
                if (ACT == 1) v = fmaxf(v, 0.f);
                if (RES) v += R[(size_t)gm * N + gn];
                C[(size_t)gm * N + gn] = v;
            }
        }
    }
}

// ---------------- bf16 MFMA split-K phase 1 (head): 64x64 tile, partials fp32 ----------------
// M,N multiples of 64; kchunk multiple of 32.
__global__ __launch_bounds__(256) void msk_k(const unsigned short* __restrict__ A,
                                             const unsigned short* __restrict__ BT,
                                             float* __restrict__ Cp, int M, int N, int K,
                                             int kchunk) {
    __shared__ unsigned short As[64 * 32];
    __shared__ unsigned short Bs[64 * 32];
    int m0 = blockIdx.y * 64, n0 = blockIdx.x * 64;
    int kbeg = blockIdx.z * kchunk;
    float* C = Cp + (size_t)blockIdx.z * M * N;
    int tid = threadIdx.x;
    int wave = tid >> 6, lane = tid & 63;
    int wm = wave * 16;
    int lrow = lane & 15, lq = lane >> 4;
    f32x4 acc[4];
    const f32x4 zz = {0.f, 0.f, 0.f, 0.f};
#pragma unroll
    for (int j = 0; j < 4; j++) acc[j] = zz;
    int r0 = tid >> 2;
    int q = tid & 3;
    for (int k0 = kbeg; k0 < kbeg + kchunk; k0 += 32) {
        *(uint4*)&As[r0 * 32 + q * 8] = *(const uint4*)(A + (size_t)(m0 + r0) * K + k0 + q * 8);
        *(uint4*)&Bs[r0 * 32 + q * 8] = *(const uint4*)(BT + (size_t)(n0 + r0) * K + k0 + q * 8);
        __syncthreads();
        bf16x8 af = *(const bf16x8*)&As[(wm + lrow) * 32 + lq * 8];
#pragma unroll
        for (int j = 0; j < 4; j++) {
            bf16x8 bfr = *(const bf16x8*)&Bs[(j * 16 + lrow) * 32 + lq * 8];
            acc[j] = __builtin_amdgcn_mfma_f32_16x16x32_bf16(af, bfr, acc[j], 0, 0, 0);
        }
        __syncthreads();
    }
#pragma unroll
    for (int j = 0; j < 4; j++) {
        int gn = n0 + j * 16 + lrow;
#pragma unroll
        for (int r = 0; r < 4; r++) {
            int gm = m0 + wm + lq * 4 + r;
            C[(size_t)gm * N + gn] = acc[j][r];
        }
    }
}

// ---------------- fused reducers (head, M=256, N=512) ----------------
// reduce S partials + bias (+residual into hbuf); then LN -> bf16 (next block's input)
// or raw bf16 copy (for pout). hbuf always updated in fp32.
template <bool RESID, bool DO_LN>
__global__ void redln_k(const float* __restrict__ Cp, const float* __restrict__ bias,
                        const float* __restrict__ ln_s, const float* __restrict__ ln_b,
                        float* __restrict__ hbuf, unsigned short* __restrict__ outbf, int S) {
    int row = blockIdx.x * 4 + (threadIdx.x >> 6);
    int lane = threadIdx.x & 63;
    float4 a0 = {0.f, 0.f, 0.f, 0.f}, a1 = a0;
    for (int s = 0; s < S; s++) {
        const float4* pp = (const float4*)(Cp + ((size_t)s * BSZ + row) * HID);
        float4 b0 = pp[lane * 2], b1 = pp[lane * 2 + 1];
        a0.x += b0.x; a0.y += b0.y; a0.z += b0.z; a0.w += b0.w;
        a1.x += b1.x; a1.y += b1.y; a1.z += b1.z; a1.w += b1.w;
    }
    const float4* bb = (const float4*)bias;
    float4 c0 = bb[lane * 2], c1 = bb[lane * 2 + 1];
    a0.x += c0.x; a0.y += c0.y; a0.z += c0.z; a0.w += c0.w;
    a1.x += c1.x; a1.y += c1.y; a1.z += c1.z; a1.w += c1.w;
    float4* hp = (float4*)(hbuf + (size_t)row * HID);
    if (RESID) {
        float4 r0 = hp[lane * 2], r1 = hp[lane * 2 + 1];
        a0.x += r0.x; a0.y += r0.y; a0.z += r0.z; a0.w += r0.w;
        a1.x += r1.x; a1.y += r1.y; a1.z += r1.z; a1.w += r1.w;
    }
    hp[lane * 2] = a0;
    hp[lane * 2 + 1] = a1;
    unsigned short* op = outbf + (size_t)row * HID;
    if (DO_LN) {
        float sum = a0.x + a0.y + a0.z + a0.w + a1.x + a1.y + a1.z + a1.w;
#pragma unroll
        for (int off = 32; off >= 1; off >>= 1) sum += __shfl_xor(sum, off);
        float mu = sum / HID;
        float d0 = a0.x - mu, d1 = a0.y - mu, d2 = a0.z - mu, d3 = a0.w - mu;
        float d4 = a1.x - mu, d5 = a1.y - mu, d6 = a1.z - mu, d7 = a1.w - mu;
        float sq = d0 * d0 + d1 * d1 + d2 * d2 + d3 * d3 + d4 * d4 + d5 * d5 + d6 * d6 + d7 * d7;
#pragma unroll
        for (int off = 32; off >= 1; off >>= 1) sq += __shfl_xor(sq, off);
        float rstd = rsqrtf(sq / HID + 1e-5f);
        const float4* sp = (const float4*)ln_s;
        const float4* bp = (const float4*)ln_b;
        float4 s0 = sp[lane * 2], s1 = sp[lane * 2 + 1];
        float4 t0 = bp[lane * 2], t1 = bp[lane * 2 + 1];
        *(ushort4*)(op + lane * 8) =
            make_ushort4(f2bf(d0 * rstd * s0.x + t0.x), f2bf(d1 * rstd * s0.y + t0.y),
                         f2bf(d2 * rstd * s0.z + t0.z), f2bf(d3 * rstd * s0.w + t0.w));
        *(ushort4*)(op + lane * 8 + 4) =
            make_ushort4(f2bf(d4 * rstd * s1.x + t1.x), f2bf(d5 * rstd * s1.y + t1.y),
                         f2bf(d6 * rstd * s1.z + t1.z), f2bf(d7 * rstd * s1.w + t1.w));
    } else {
        *(ushort4*)(op + lane * 8) =
            make_ushort4(f2bf(a0.x), f2bf(a0.y), f2bf(a0.z), f2bf(a0.w));
        *(ushort4*)(op + lane * 8 + 4) =
            make_ushort4(f2bf(a1.x), f2bf(a1.y), f2bf(a1.z), f2bf(a1.w));
    }
}

// elementwise reduce + bias + (gelu) -> bf16   (w1 -> z1bf, pout -> projb)
template <int ACT>
__global__ void redbf_k(const float* __restrict__ Cp, const float* __restrict__ bias,
                        unsigned short* __restrict__ out, int M, int N, int S) {
    int i = blockIdx.x * 256 + threadIdx.x;
    int MN4 = M * N / 4;
    if (i >= MN4) return;
    float4 a = ((const float4*)Cp)[i];
    for (int s = 1; s < S; s++) {
        float4 b = ((const float4*)Cp)[(size_t)s * MN4 + i];
        a.x += b.x; a.y += b.y; a.z += b.z; a.w += b.w;
    }
    int n = (i * 4) % N;
    float4 b4 = *(const float4*)(bias + n);
    a.x += b4.x; a.y += b4.y; a.z += b4.z; a.w += b4.w;
    if (ACT == 2) {
        const float c = 0.70710678118654752f;
        a.x = 0.5f * a.x * (1.f + erff(a.x * c));
        a.y = 0.5f * a.y * (1.f + erff(a.y * c));
        a.z = 0.5f * a.z * (1.f + erff(a.z * c));
        a.w = 0.5f * a.w * (1.f + erff(a.w * c));
    }
    *(ushort4*)(out + (size_t)i * 4) = make_ushort4(f2bf(a.x), f2bf(a.y), f2bf(a.z), f2bf(a.w));
}

// post reduce + bias + OOV row select -> bf16 (M=256, N=256)
__global__ void redoov_k(const float* __restrict__ Cp, const float* __restrict__ bias,
                         const int* __restrict__ idx, const float* __restrict__ oov_emb,
                         unsigned short* __restrict__ out, int S) {
    int row = blockIdx.x * 4 + (threadIdx.x >> 6);
    int lane = threadIdx.x & 63;
    float4 a = {0.f, 0.f, 0.f, 0.f};
    for (int s = 0; s < S; s++) {
        float4 b = ((const float4*)(Cp + ((size_t)s * BSZ + row) * GDIM))[lane];
        a.x += b.x; a.y += b.y; a.z += b.z; a.w += b.w;
    }
    float4 b4 = ((const float4*)bias)[lane];
    a.x += b4.x; a.y += b4.y; a.z += b4.z; a.w += b4.w;
    if (idx[row] < 0) a = ((const float4*)oov_emb)[lane];
    *(ushort4*)(out + (size_t)row * GDIM + lane * 4) =
        make_ushort4(f2bf(a.x), f2bf(a.y), f2bf(a.z), f2bf(a.w));
}

// OOV-safe gather -> bf16
__global__ void gatherb_k(const int* __restrict__ idx, const float* __restrict__ X,
                          unsigned short* __restrict__ Y) {
    int b = blockIdx.x;
    int lane = threadIdx.x;
    int id = idx[b];
    int safe = id < 0 ? 0 : id;
    float4 v = ((const float4*)(X + (size_t)safe * GDIM))[lane];
    *(ushort4*)(Y + (size_t)b * GDIM + lane * 4) =
        make_ushort4(f2bf(v.x), f2bf(v.y), f2bf(v.z), f2bf(v.w));
}

// ---------------- launch ----------------
extern "C" void kernel_launch(void* const* d_in, const int* in_sizes, int n_in,
                              void* d_out, int out_size, void* d_ws, size_t ws_size,
                              hipStream_t stream) {
    const int* node_indices = (const int*)d_in[0];
    const int* edge_src = (const int*)d_in[1];
    const int* edge_dst = edge_src + NEDGES;
    const float* edge_w = (const float*)d_in[2];
    const float* partial_emb = (const float*)d_in[3];
    const float* oov_emb = (const float*)d_in[4];
    const float* gnn_ln_s = (const float*)d_in[5];
    const float* gnn_ln_b = (const float*)d_in[6];
    const float* gnn_w = (const float*)d_in[7];
    const float* gnn_b = (const float*)d_in[8];
    const float* post_w = (const float*)d_in[9];
    const float* post_b = (const float*)d_in[10];
    const float* pin_w = (const float*)d_in[11];
    const float* pin_b = (const float*)d_in[12];
    const float* blk_ln_s = (const float*)d_in[13];
    const float* blk_ln_b = (const float*)d_in[14];
    const float* blk_w1 = (const float*)d_in[15];
    const float* blk_b1 = (const float*)d_in[16];
    const float* blk_w2 = (const float*)d_in[17];
    const float* blk_b2 = (const float*)d_in[18];
    const float* pout_w = (const float*)d_in[19];
    const float* pout_b = (const float*)d_in[20];
    const float* gene = (const float*)d_in[21];
    float* out = (float*)d_out;

    char* p = (char*)d_ws;
    auto alloc = [&](size_t bytes) {
        char* r = p;
        p += (bytes + 255) & ~(size_t)255;
        return r;
    };
    int* counts = (int*)alloc(NNODES * 4);
    int* incl = (int*)alloc(NNODES * 4);
    int* bsums = (int*)alloc(128 * 4);
    int* boffs = (int*)alloc(128 * 4);
    int* row_start = (int*)alloc(NNODES * 4);
    int* cursor = (int*)alloc(NNODES * 4);
    int2* epack = (int2*)alloc((size_t)NEDGES * 8);
    // 'part': GNN phase = ln_bf + aggbf (bf16); head phase = split-K fp32 partials (max 8 MB)
    float* part = (float*)alloc((size_t)NNODES * GDIM * 4);
    unsigned short* ln_bf = (unsigned short*)part;
    unsigned short* aggbf = (unsigned short*)((char*)part + (size_t)NNODES * GDIM * 2);
    float* xa = (float*)alloc((size_t)NNODES * GDIM * 4);
    float* xb = (float*)alloc((size_t)NNODES * GDIM * 4);
    float* hbuf = (float*)alloc((size_t)BSZ * HID * 4);
    unsigned short* pertinbf = (unsigned short*)alloc((size_t)BSZ * GDIM * 2);
    unsigned short* pertbf = (unsigned short*)alloc((size_t)BSZ * GDIM * 2);
    unsigned short* zlnbf = (unsigned short*)alloc((size_t)BSZ * HID * 2);
    unsigned short* z1bf = (unsigned short*)alloc((size_t)BSZ * INNER * 2);
    unsigned short* hbufbf = (unsigned short*)alloc((size_t)BSZ * HID * 2);
    unsigned short* projb = (unsigned short*)alloc((size_t)BSZ * NCLS * RANK * 2);
    unsigned short* gnnT = (unsigned short*)alloc((size_t)3 * GDIM * GDIM * 2);
    unsigned short* postT = (unsigned short*)alloc((size_t)GDIM * GDIM * 2);
    unsigned short* pinT = (unsigned short*)alloc((size_t)HID * GDIM * 2);
    unsigned short* w1T = (unsigned short*)alloc((size_t)6 * INNER * HID * 2);
    unsigned short* w2T = (unsigned short*)alloc((size_t)6 * HID * INNER * 2);
    unsigned short* poutT = (unsigned short*)alloc((size_t)NCLS * RANK * HID * 2);
    unsigned short* geneb = (unsigned short*)alloc((size_t)NGENES * RANK * 2);

    const int EB = (NEDGES + 255) / 256;
    const int NB = (NNODES + 255) / 256;

    // weight conversions (per launch; inputs restored every call)
    tconv_k<<<dim3(GDIM / 32, GDIM / 32, 3), dim3(32, 8), 0, stream>>>(gnn_w, gnnT, GDIM, GDIM);
    tconv_k<<<dim3(GDIM / 32, GDIM / 32, 1), dim3(32, 8), 0, stream>>>(post_w, postT, GDIM, GDIM);
    tconv_k<<<dim3(HID / 32, GDIM / 32, 1), dim3(32, 8), 0, stream>>>(pin_w, pinT, GDIM, HID);
    tconv_k<<<dim3(INNER / 32, HID / 32, 6), dim3(32, 8), 0, stream>>>(blk_w1, w1T, HID, INNER);
    tconv_k<<<dim3(HID / 32, INNER / 32, 6), dim3(32, 8), 0, stream>>>(blk_w2, w2T, INNER, HID);
    tconv_k<<<dim3((NCLS * RANK) / 32, HID / 32, 1), dim3(32, 8), 0, stream>>>(pout_w, poutT, HID,
                                                                               NCLS * RANK);
    cvtb_k<<<(NGENES * RANK / 8 + 255) / 256, 256, 0, stream>>>(gene, geneb, NGENES * RANK / 8);

    // CSR build
    hipMemsetAsync(counts, 0, NNODES * 4, stream);
    hist_k<<<EB, 256, 0, stream>>>(edge_dst, counts, NEDGES);
    scan1_k<<<NB, 256, 0, stream>>>(counts, incl, bsums, NNODES);
    scan2_k<<<1, 128, 0, stream>>>(bsums, boffs, NB);
    scan3_k<<<NB, 256, 0, stream>>>(incl, counts, boffs, row_start, cursor, NNODES);
    scatter_k<<<EB, 256, 0, stream>>>(edge_src, edge_dst, edge_w, cursor, epack, NEDGES);

    // GNN tail: 3 layers
    const float* x_in = partial_emb;
    float* bufs[2] = {xa, xb};
    for (int i = 0; i < 3; i++) {
        lnb_k<<<(NNODES + 3) / 4, 256, 0, stream>>>(x_in, gnn_ln_s + i * GDIM,
                                                    gnn_ln_b + i * GDIM, ln_bf, NNODES);
        aggb_k<<<(NNODES + 3) / 4, 256, 0, stream>>>(row_start, counts, epack, ln_bf, aggbf,
                                                     NNODES);
        float* x_out = bufs[i & 1];
        mgemm_k<1, true, true><<<dim3(GDIM / 128, (NNODES + 127) / 128), 256, 0, stream>>>(
            aggbf, gnnT + (size_t)i * GDIM * GDIM, gnn_b + i * GDIM, x_in, x_out, NNODES, GDIM,
            GDIM);
        x_in = x_out;
    }

    // gather -> post (split-K MFMA) -> OOV fuse -> bf16 pert
    gatherb_k<<<BSZ, 64, 0, stream>>>(node_indices, x_in, pertinbf);
    msk_k<<<dim3(GDIM / 64, BSZ / 64, 4), 256, 0, stream>>>(pertinbf, postT, part, BSZ, GDIM,
                                                            GDIM, GDIM / 4);
    redoov_k<<<BSZ / 4, 256, 0, stream>>>(part, post_b, node_indices, oov_emb, pertbf, 4);

    // pin -> hbuf (fp32) + LN(block0) -> zlnbf
    msk_k<<<dim3(HID / 64, BSZ / 64, 4), 256, 0, stream>>>(pertbf, pinT, part, BSZ, HID, GDIM,
                                                           GDIM / 4);
    redln_k<false, true><<<BSZ / 4, 256, 0, stream>>>(part, pin_b, blk_ln_s, blk_ln_b, hbuf,
                                                      zlnbf, 4);

    // 6 head blocks
    for (int i = 0; i < 6; i++) {
        msk_k<<<dim3(INNER / 64, BSZ / 64, 4), 256, 0, stream>>>(
            zlnbf, w1T + (size_t)i * INNER * HID, part, BSZ, INNER, HID, HID / 4);
        redbf_k<2><<<(BSZ * INNER / 4 + 255) / 256, 256, 0, stream>>>(part, blk_b1 + i * INNER,
                                                                      z1bf, BSZ, INNER, 4);
        msk_k<<<dim3(HID / 64, BSZ / 64, 8), 256, 0, stream>>>(
            z1bf, w2T + (size_t)i * HID * INNER, part, BSZ, HID, INNER, INNER / 8);
        if (i < 5) {
            redln_k<true, true><<<BSZ / 4, 256, 0, stream>>>(
                part, blk_b2 + i * HID, blk_ln_s + (i + 1) * HID, blk_ln_b + (i + 1) * HID, hbuf,
                zlnbf, 8);
        } else {
            redln_k<true, false><<<BSZ / 4, 256, 0, stream>>>(part, blk_b2 + i * HID, nullptr,
                                                              nullptr, hbuf, hbufbf, 8);
        }
    }

    // pout -> projb (bf16)
    msk_k<<<dim3((NCLS * RANK) / 64, BSZ / 64, 4), 256, 0, stream>>>(hbufbf, poutT, part, BSZ,
                                                                     NCLS * RANK, HID, HID / 4);
    redbf_k<0><<<(BSZ * NCLS * RANK / 4 + 255) / 256, 256, 0, stream>>>(part, pout_b, projb, BSZ,
                                                                        NCLS * RANK, 4);

    // logits
    mgemm_k<0, false, false><<<dim3((NGENES + 127) / 128, (BSZ * NCLS) / 128), 256, 0, stream>>>(
        projb, geneb, nullptr, nullptr, out, BSZ * NCLS, NGENES, RANK);
}

// Round 5
// 612.201 us; speedup vs baseline: 3.2034x; 1.1073x over previous
//
#include <hip/hip_runtime.h>
#include <hip/hip_bf16.h>
#include <math.h>

#define NNODES 20000
#define NEDGES 640000
#define BSZ 256
#define GDIM 256
#define HID 512
#define INNER 2048
#define RANK 512
#define NCLS 3
#define NGENES 6640

typedef __attribute__((ext_vector_type(8))) short bf16x8;
typedef __attribute__((ext_vector_type(4))) float f32x4;

__device__ inline float bf2f(unsigned short u) {
    return __uint_as_float(((unsigned)u) << 16);
}
__device__ inline unsigned short f2bf(float f) {
    unsigned u = __float_as_uint(f);
    u = u + 0x7fff + ((u >> 16) & 1);   // RNE
    return (unsigned short)(u >> 16);
}

// ---------------- CSR build ----------------
__global__ void hist_k(const int* __restrict__ dst, int* __restrict__ counts, int E) {
    int e = blockIdx.x * 256 + threadIdx.x;
    if (e < E) atomicAdd(&counts[dst[e]], 1);
}

__global__ void scan1_k(const int* __restrict__ counts, int* __restrict__ incl,
                        int* __restrict__ bsums, int n) {
    __shared__ int s[256];
    int i = blockIdx.x * 256 + threadIdx.x;
    int v = (i < n) ? counts[i] : 0;
    s[threadIdx.x] = v;
    __syncthreads();
    for (int off = 1; off < 256; off <<= 1) {
        int t = (threadIdx.x >= off) ? s[threadIdx.x - off] : 0;
        __syncthreads();
        s[threadIdx.x] += t;
        __syncthreads();
    }
    if (i < n) incl[i] = s[threadIdx.x];
    if (threadIdx.x == 255) bsums[blockIdx.x] = s[255];
}

__global__ void scan2_k(const int* __restrict__ bsums, int* __restrict__ boffs, int nb) {
    __shared__ int s[128];
    int tid = threadIdx.x;
    int v = (tid < nb) ? bsums[tid] : 0;
    s[tid] = v;
    __syncthreads();
    for (int off = 1; off < 128; off <<= 1) {
        int t = (tid >= off) ? s[tid - off] : 0;
        __syncthreads();
        s[tid] += t;
        __syncthreads();
    }
    if (tid < nb) boffs[tid] = s[tid] - v;
}

__global__ void scan3_k(const int* __restrict__ incl, const int* __restrict__ counts,
                        const int* __restrict__ boffs, int* __restrict__ row_start,
                        int* __restrict__ cursor, int n) {
    int i = blockIdx.x * 256 + threadIdx.x;
    if (i < n) {
        int st = incl[i] - counts[i] + boffs[blockIdx.x];
        row_start[i] = st;
        cursor[i] = st;
    }
}

__global__ void scatter_k(const int* __restrict__ src, const int* __restrict__ dst,
                          const float* __restrict__ w, int* __restrict__ cursor,
                          int2* __restrict__ ep, int E) {
    int e = blockIdx.x * 256 + threadIdx.x;
    if (e < E) {
        int d = dst[e];
        int p = atomicAdd(&cursor[d], 1);
        ep[p] = make_int2(src[e], __float_as_int(w[e]));
    }
}

// ---------------- conversions ----------------
__global__ void cvtb_k(const float* __restrict__ X, unsigned short* __restrict__ Y, int n8) {
    int i = blockIdx.x * 256 + threadIdx.x;
    if (i >= n8) return;
    const float4* xp = (const float4*)X;
    float4 a = xp[i * 2], b = xp[i * 2 + 1];
    *(ushort4*)(Y + (size_t)i * 8) = make_ushort4(f2bf(a.x), f2bf(a.y), f2bf(a.z), f2bf(a.w));
    *(ushort4*)(Y + (size_t)i * 8 + 4) = make_ushort4(f2bf(b.x), f2bf(b.y), f2bf(b.z), f2bf(b.w));
}

// W [K][N] fp32 -> WT [N][K] bf16, 32x32 LDS tiles, grid.z = layer
__global__ void tconv_k(const float* __restrict__ W, unsigned short* __restrict__ WT, int K,
                        int N) {
    __shared__ float s[32][33];
    const float* Wl = W + (size_t)blockIdx.z * K * N;
    unsigned short* WTl = WT + (size_t)blockIdx.z * K * N;
    int k0 = blockIdx.y * 32, n0 = blockIdx.x * 32;
#pragma unroll
    for (int i = 0; i < 4; i++)
        s[threadIdx.y + 8 * i][threadIdx.x] =
            Wl[(size_t)(k0 + threadIdx.y + 8 * i) * N + n0 + threadIdx.x];
    __syncthreads();
#pragma unroll
    for (int i = 0; i < 4; i++)
        WTl[(size_t)(n0 + threadIdx.y + 8 * i) * K + k0 + threadIdx.x] =
            f2bf(s[threadIdx.x][threadIdx.y + 8 * i]);
}

// ---------------- GNN LayerNorm (D=256), bf16 out ----------------
__global__ void lnb_k(const float* __restrict__ X, const float* __restrict__ sc,
                      const float* __restrict__ bi, unsigned short* __restrict__ Y, int M) {
    int row = blockIdx.x * 4 + (threadIdx.x >> 6);
    int lane = threadIdx.x & 63;
    if (row >= M) return;
    float4 v = ((const float4*)(X + (size_t)row * GDIM))[lane];
    float sum = v.x + v.y + v.z + v.w;
#pragma unroll
    for (int off = 32; off >= 1; off >>= 1) sum += __shfl_xor(sum, off);
    float mu = sum / GDIM;
    float a = v.x - mu, b = v.y - mu, c = v.z - mu, d = v.w - mu;
    float sq = a * a + b * b + c * c + d * d;
#pragma unroll
    for (int off = 32; off >= 1; off >>= 1) sq += __shfl_xor(sq, off);
    float rstd = rsqrtf(sq / GDIM + 1e-5f);
    float4 s4 = ((const float4*)sc)[lane];
    float4 b4 = ((const float4*)bi)[lane];
    *(ushort4*)(Y + (size_t)row * GDIM + lane * 4) =
        make_ushort4(f2bf(a * rstd * s4.x + b4.x), f2bf(b * rstd * s4.y + b4.y),
                     f2bf(c * rstd * s4.z + b4.z), f2bf(d * rstd * s4.w + b4.w));
}

// ---------------- CSR aggregation, 16-deep MLP unroll ----------------
__device__ inline void agg_row(int beg, int cnt, int lane, const int2* __restrict__ ep,
                               const unsigned short* __restrict__ H, float& a0, float& a1,
                               float& a2, float& a3) {
    int t = 0;
    for (; t + 16 <= cnt; t += 16) {
        int2 e[16];
#pragma unroll
        for (int u = 0; u < 16; u++) e[u] = ep[beg + t + u];
        ushort4 v[16];
#pragma unroll
        for (int u = 0; u < 16; u++)
            v[u] = *(const ushort4*)(H + (size_t)e[u].x * GDIM + lane * 4);
#pragma unroll
        for (int u = 0; u < 16; u++) {
            float w = __int_as_float(e[u].y);
            a0 = fmaf(bf2f(v[u].x), w, a0);
            a1 = fmaf(bf2f(v[u].y), w, a1);
            a2 = fmaf(bf2f(v[u].z), w, a2);
            a3 = fmaf(bf2f(v[u].w), w, a3);
        }
    }
    for (; t + 4 <= cnt; t += 4) {
        int2 e[4];
#pragma unroll
        for (int u = 0; u < 4; u++) e[u] = ep[beg + t + u];
        ushort4 v[4];
#pragma unroll
        for (int u = 0; u < 4; u++)
            v[u] = *(const ushort4*)(H + (size_t)e[u].x * GDIM + lane * 4);
#pragma unroll
        for (int u = 0; u < 4; u++) {
            float w = __int_as_float(e[u].y);
            a0 = fmaf(bf2f(v[u].x), w, a0);
            a1 = fmaf(bf2f(v[u].y), w, a1);
            a2 = fmaf(bf2f(v[u].z), w, a2);
            a3 = fmaf(bf2f(v[u].w), w, a3);
        }
    }
    for (; t < cnt; t++) {
        int2 e = ep[beg + t];
        float w = __int_as_float(e.y);
        ushort4 v = *(const ushort4*)(H + (size_t)e.x * GDIM + lane * 4);
        a0 = fmaf(bf2f(v.x), w, a0);
        a1 = fmaf(bf2f(v.y), w, a1);
        a2 = fmaf(bf2f(v.z), w, a2);
        a3 = fmaf(bf2f(v.w), w, a3);
    }
}

__global__ void aggb_k(const int* __restrict__ row_start, const int* __restrict__ counts,
                       const int2* __restrict__ ep, const unsigned short* __restrict__ H,
                       unsigned short* __restrict__ AGG, int n) {
    int row = blockIdx.x * 4 + (threadIdx.x >> 6);
    int lane = threadIdx.x & 63;
    if (row >= n) return;
    float a0 = 0.f, a1 = 0.f, a2 = 0.f, a3 = 0.f;
    agg_row(row_start[row], counts[row], lane, ep, H, a0, a1, a2, a3);
    *(ushort4*)(AGG + (size_t)row * GDIM + lane * 4) =
        make_ushort4(f2bf(a0), f2bf(a1), f2bf(a2), f2bf(a3));
}

// layer-3: aggregate only the 256 selected rows
__global__ void aggsel_k(const int* __restrict__ idx, const int* __restrict__ row_start,
                         const int* __restrict__ counts, const int2* __restrict__ ep,
                         const unsigned short* __restrict__ H, unsigned short* __restrict__ AGG) {
    int b = blockIdx.x * 4 + (threadIdx.x >> 6);
    int lane = threadIdx.x & 63;
    int id = idx[b];
    int row = id < 0 ? 0 : id;
    float a0 = 0.f, a1 = 0.f, a2 = 0.f, a3 = 0.f;
    agg_row(row_start[row], counts[row], lane, ep, H, a0, a1, a2, a3);
    *(ushort4*)(AGG + (size_t)b * GDIM + lane * 4) =
        make_ushort4(f2bf(a0), f2bf(a1), f2bf(a2), f2bf(a3));
}

// ---------------- bf16 MFMA GEMM (full-K, fp32 out, fused epilogue) — GNN L1/L2 & logits ----------------
// 128x128 tile, 4 waves 2x2, each 64x64. BT = [N][K] bf16.
template <int ACT, bool RES, bool BIAS>
__global__ __launch_bounds__(256) void mgemm_k(const unsigned short* __restrict__ A,
                                               const unsigned short* __restrict__ BT,
                                               const float* __restrict__ bias,
                                               const float* __restrict__ R,
                                               float* __restrict__ C, int M, int N, int K) {
    __shared__ unsigned short As[128 * 32];
    __shared__ unsigned short Bs[128 * 32];
    int m0 = blockIdx.y * 128, n0 = blockIdx.x * 128;
    int tid = threadIdx.x;
    int wave = tid >> 6, lane = tid & 63;
    int wm = (wave >> 1) * 64, wn = (wave & 1) * 64;
    int lrow = lane & 15, lq = lane >> 4;

    f32x4 acc[4][4];
    const f32x4 zz = {0.f, 0.f, 0.f, 0.f};
#pragma unroll
    for (int i = 0; i < 4; i++)
#pragma unroll
        for (int j = 0; j < 4; j++) acc[i][j] = zz;

    int r0 = tid >> 2;
    int q = tid & 3;

    for (int k0 = 0; k0 < K; k0 += 32) {
#pragma unroll
        for (int p = 0; p < 2; p++) {
            int row = r0 + p * 64;
            int gm = m0 + row;
            uint4 va = make_uint4(0, 0, 0, 0);
            if (gm < M) va = *(const uint4*)(A + (size_t)gm * K + k0 + q * 8);
            *(uint4*)&As[row * 32 + q * 8] = va;
            int gn = n0 + row;
            uint4 vb = make_uint4(0, 0, 0, 0);
            if (gn < N) vb = *(const uint4*)(BT + (size_t)gn * K + k0 + q * 8);
            *(uint4*)&Bs[row * 32 + q * 8] = vb;
        }
        __syncthreads();
        bf16x8 af[4], bf[4];
#pragma unroll
        for (int i = 0; i < 4; i++)
            af[i] = *(const bf16x8*)&As[(wm + i * 16 + lrow) * 32 + lq * 8];
#pragma unroll
        for (int j = 0; j < 4; j++)
            bf[j] = *(const bf16x8*)&Bs[(wn + j * 16 + lrow) * 32 + lq * 8];
#pragma unroll
        for (int i = 0; i < 4; i++)
#pragma unroll
            for (int j = 0; j < 4; j++)
                acc[i][j] =
                    __builtin_amdgcn_mfma_f32_16x16x32_bf16(af[i], bf[j], acc[i][j], 0, 0, 0);
        __syncthreads();
    }

#pragma unroll
    for (int i = 0; i < 4; i++) {
#pragma unroll
        for (int j = 0; j < 4; j++) {
            int gn = n0 + wn + j * 16 + lrow;
            if (gn >= N) continue;
            float bv = BIAS ? bias[gn] : 0.f;
#pragma unroll
            for (int r = 0; r < 4; r++) {
                int gm = m0 + wm + i * 16 + lq * 4 + r;
                if (gm >= M) continue;
                float v = acc[i][j][r] + bv;
                if (ACT == 1) v = fmaxf(v, 0.f);
                if (RES) v += R[(size_t)gm * N + gn];
                C[(size_t)gm * N + gn] = v;
            }
        }
    }
}

// ---------------- bf16 MFMA full-K, bf16 out, fused epilogue (head) ----------------
// 64x64 tile, 4 waves stacked in M. M,N multiples of 64.
// ACT: 0 none, 1 relu, 2 gelu. EPI: 0 plain, 1 OOV-replace (aux=oov_emb),
// 2 indexed-residual after act (aux=R base [NNODES x N], idx-mapped rows).
template <int ACT, int EPI>
__global__ __launch_bounds__(256) void mfull_k(const unsigned short* __restrict__ A,
                                               const unsigned short* __restrict__ BT,
                                               const float* __restrict__ bias,
                                               const int* __restrict__ idx,
                                               const float* __restrict__ aux,
                                               unsigned short* __restrict__ O, int M, int N,
                                               int K) {
    __shared__ unsigned short As[64 * 32];
    __shared__ unsigned short Bs[64 * 32];
    int m0 = blockIdx.y * 64, n0 = blockIdx.x * 64;
    int tid = threadIdx.x;
    int wave = tid >> 6, lane = tid & 63;
    int wm = wave * 16;
    int lrow = lane & 15, lq = lane >> 4;
    f32x4 acc[4];
    const f32x4 zz = {0.f, 0.f, 0.f, 0.f};
#pragma unroll
    for (int j = 0; j < 4; j++) acc[j] = zz;
    int r0 = tid >> 2;
    int q = tid & 3;
    for (int k0 = 0; k0 < K; k0 += 32) {
        *(uint4*)&As[r0 * 32 + q * 8] = *(const uint4*)(A + (size_t)(m0 + r0) * K + k0 + q * 8);
        *(uint4*)&Bs[r0 * 32 + q * 8] = *(const uint4*)(BT + (size_t)(n0 + r0) * K + k0 + q * 8);
        __syncthreads();
        bf16x8 af = *(const bf16x8*)&As[(wm + lrow) * 32 + lq * 8];
#pragma unroll
        for (int j = 0; j < 4; j++) {
            bf16x8 bfr = *(const bf16x8*)&Bs[(j * 16 + lrow) * 32 + lq * 8];
            acc[j] = __builtin_amdgcn_mfma_f32_16x16x32_bf16(af, bfr, acc[j], 0, 0, 0);
        }
        __syncthreads();
    }
#pragma unroll
    for (int j = 0; j < 4; j++) {
        int gn = n0 + j * 16 + lrow;
        float bv = bias[gn];
#pragma unroll
        for (int r = 0; r < 4; r++) {
            int gm = m0 + wm + lq * 4 + r;
            float v = acc[j][r] + bv;
            if (ACT == 1) v = fmaxf(v, 0.f);
            if (ACT == 2) v = 0.5f * v * (1.f + erff(v * 0.70710678118654752f));
            if (EPI == 2) {
                int id = idx[gm];
                int safe = id < 0 ? 0 : id;
                v += aux[(size_t)safe * N + gn];
            }
            if (EPI == 1) {
                if (idx[gm] < 0) v = aux[gn];
            }
            O[(size_t)gm * N + gn] = f2bf(v);
        }
    }
}

// ---------------- bf16 MFMA split-K phase 1: 64x64 tile, fp32 partials ----------------
__global__ __launch_bounds__(256) void msk_k(const unsigned short* __restrict__ A,
                                             const unsigned short* __restrict__ BT,
                                             float* __restrict__ Cp, int M, int N, int K,
                                             int kchunk) {
    __shared__ unsigned short As[64 * 32];
    __shared__ unsigned short Bs[64 * 32];
    int m0 = blockIdx.y * 64, n0 = blockIdx.x * 64;
    int kbeg = blockIdx.z * kchunk;
    float* C = Cp + (size_t)blockIdx.z * M * N;
    int tid = threadIdx.x;
    int wave = tid >> 6, lane = tid & 63;
    int wm = wave * 16;
    int lrow = lane & 15, lq = lane >> 4;
    f32x4 acc[4];
    const f32x4 zz = {0.f, 0.f, 0.f, 0.f};
#pragma unroll
    for (int j = 0; j < 4; j++) acc[j] = zz;
    int r0 = tid >> 2;
    int q = tid & 3;
    for (int k0 = kbeg; k0 < kbeg + kchunk; k0 += 32) {
        *(uint4*)&As[r0 * 32 + q * 8] = *(const uint4*)(A + (size_t)(m0 + r0) * K + k0 + q * 8);
        *(uint4*)&Bs[r0 * 32 + q * 8] = *(const uint4*)(BT + (size_t)(n0 + r0) * K + k0 + q * 8);
        __syncthreads();
        bf16x8 af = *(const bf16x8*)&As[(wm + lrow) * 32 + lq * 8];
#pragma unroll
        for (int j = 0; j < 4; j++) {
            bf16x8 bfr = *(const bf16x8*)&Bs[(j * 16 + lrow) * 32 + lq * 8];
            acc[j] = __builtin_amdgcn_mfma_f32_16x16x32_bf16(af, bfr, acc[j], 0, 0, 0);
        }
        __syncthreads();
    }
#pragma unroll
    for (int j = 0; j < 4; j++) {
        int gn = n0 + j * 16 + lrow;
#pragma unroll
        for (int r = 0; r < 4; r++) {
            int gm = m0 + wm + lq * 4 + r;
            C[(size_t)gm * N + gn] = acc[j][r];
        }
    }
}

// ---------------- fused reducer (head, M=256, N=512): reduce + bias (+res) -> hbuf, LN -> bf16 ----------------
template <bool RESID, bool DO_LN>
__global__ void redln_k(const float* __restrict__ Cp, const float* __restrict__ bias,
                        const float* __restrict__ ln_s, const float* __restrict__ ln_b,
                        float* __restrict__ hbuf, unsigned short* __restrict__ outbf, int S) {
    int row = blockIdx.x * 4 + (threadIdx.x >> 6);
    int lane = threadIdx.x & 63;
    float4 a0 = {0.f, 0.f, 0.f, 0.f}, a1 = a0;
    for (int s = 0; s < S; s++) {
        const float4* pp = (const float4*)(Cp + ((size_t)s * BSZ + row) * HID);
        float4 b0 = pp[lane * 2], b1 = pp[lane * 2 + 1];
        a0.x += b0.x; a0.y += b0.y; a0.z += b0.z; a0.w += b0.w;
        a1.x += b1.x; a1.y += b1.y; a1.z += b1.z; a1.w += b1.w;
    }
    const float4* bb = (const float4*)bias;
    float4 c0 = bb[lane * 2], c1 = bb[lane * 2 + 1];
    a0.x += c0.x; a0.y += c0.y; a0.z += c0.z; a0.w += c0.w;
    a1.x += c1.x; a1.y += c1.y; a1.z += c1.z; a1.w += c1.w;
    float4* hp = (float4*)(hbuf + (size_t)row * HID);
    if (RESID) {
        float4 r0 = hp[lane * 2], r1 = hp[lane * 2 + 1];
        a0.x += r0.x; a0.y += r0.y; a0.z += r0.z; a0.w += r0.w;
        a1.x += r1.x; a1.y += r1.y; a1.z += r1.z; a1.w += r1.w;
    }
    hp[lane * 2] = a0;
    hp[lane * 2 + 1] = a1;
    unsigned short* op = outbf + (size_t)row * HID;
    if (DO_LN) {
        float sum = a0.x + a0.y + a0.z + a0.w + a1.x + a1.y + a1.z + a1.w;
#pragma unroll
        for (int off = 32; off >= 1; off >>= 1) sum += __shfl_xor(sum, off);
        float mu = sum / HID;
        float d0 = a0.x - mu, d1 = a0.y - mu, d2 = a0.z - mu, d3 = a0.w - mu;
        float d4 = a1.x - mu, d5 = a1.y - mu, d6 = a1.z - mu, d7 = a1.w - mu;
        float sq = d0 * d0 + d1 * d1 + d2 * d2 + d3 * d3 + d4 * d4 + d5 * d5 + d6 * d6 + d7 * d7;
#pragma unroll
        for (int off = 32; off >= 1; off >>= 1) sq += __shfl_xor(sq, off);
        float rstd = rsqrtf(sq / HID + 1e-5f);
        const float4* sp = (const float4*)ln_s;
        const float4* bp = (const float4*)ln_b;
        float4 s0 = sp[lane * 2], s1 = sp[lane * 2 + 1];
        float4 t0 = bp[lane * 2], t1 = bp[lane * 2 + 1];
        *(ushort4*)(op + lane * 8) =
            make_ushort4(f2bf(d0 * rstd * s0.x + t0.x), f2bf(d1 * rstd * s0.y + t0.y),
                         f2bf(d2 * rstd * s0.z + t0.z), f2bf(d3 * rstd * s0.w + t0.w));
        *(ushort4*)(op + lane * 8 + 4) =
            make_ushort4(f2bf(d4 * rstd * s1.x + t1.x), f2bf(d5 * rstd * s1.y + t1.y),
                         f2bf(d6 * rstd * s1.z + t1.z), f2bf(d7 * rstd * s1.w + t1.w));
    } else {
        *(ushort4*)(op + lane * 8) = make_ushort4(f2bf(a0.x), f2bf(a0.y), f2bf(a0.z), f2bf(a0.w));
        *(ushort4*)(op + lane * 8 + 4) =
            make_ushort4(f2bf(a1.x), f2bf(a1.y), f2bf(a1.z), f2bf(a1.w));
    }
}

// ---------------- launch ----------------
extern "C" void kernel_launch(void* const* d_in, const int* in_sizes, int n_in,
                              void* d_out, int out_size, void* d_ws, size_t ws_size,
                              hipStream_t stream) {
    const int* node_indices = (const int*)d_in[0];
    const int* edge_src = (const int*)d_in[1];
    const int* edge_dst = edge_src + NEDGES;
    const float* edge_w = (const float*)d_in[2];
    const float* partial_emb = (const float*)d_in[3];
    const float* oov_emb = (const float*)d_in[4];
    const float* gnn_ln_s = (const float*)d_in[5];
    const float* gnn_ln_b = (const float*)d_in[6];
    const float* gnn_w = (const float*)d_in[7];
    const float* gnn_b = (const float*)d_in[8];
    const float* post_w = (const float*)d_in[9];
    const float* post_b = (const float*)d_in[10];
    const float* pin_w = (const float*)d_in[11];
    const float* pin_b = (const float*)d_in[12];
    const float* blk_ln_s = (const float*)d_in[13];
    const float* blk_ln_b = (const float*)d_in[14];
    const float* blk_w1 = (const float*)d_in[15];
    const float* blk_b1 = (const float*)d_in[16];
    const float* blk_w2 = (const float*)d_in[17];
    const float* blk_b2 = (const float*)d_in[18];
    const float* pout_w = (const float*)d_in[19];
    const float* pout_b = (const float*)d_in[20];
    const float* gene = (const float*)d_in[21];
    float* out = (float*)d_out;

    char* p = (char*)d_ws;
    auto alloc = [&](size_t bytes) {
        char* r = p;
        p += (bytes + 255) & ~(size_t)255;
        return r;
    };
    int* counts = (int*)alloc(NNODES * 4);
    int* incl = (int*)alloc(NNODES * 4);
    int* bsums = (int*)alloc(128 * 4);
    int* boffs = (int*)alloc(128 * 4);
    int* row_start = (int*)alloc(NNODES * 4);
    int* cursor = (int*)alloc(NNODES * 4);
    int2* epack = (int2*)alloc((size_t)NEDGES * 8);
    // 'part': GNN phase = ln_bf + aggbf (bf16); head phase = split-K fp32 partials
    float* part = (float*)alloc((size_t)NNODES * GDIM * 4);
    unsigned short* ln_bf = (unsigned short*)part;
    unsigned short* aggbf = (unsigned short*)((char*)part + (size_t)NNODES * GDIM * 2);
    float* xa = (float*)alloc((size_t)NNODES * GDIM * 4);
    float* xb = (float*)alloc((size_t)NNODES * GDIM * 4);
    float* hbuf = (float*)alloc((size_t)BSZ * HID * 4);
    unsigned short* aggselb = (unsigned short*)alloc((size_t)BSZ * GDIM * 2);
    unsigned short* pertinbf = (unsigned short*)alloc((size_t)BSZ * GDIM * 2);
    unsigned short* pertbf = (unsigned short*)alloc((size_t)BSZ * GDIM * 2);
    unsigned short* zlnbf = (unsigned short*)alloc((size_t)BSZ * HID * 2);
    unsigned short* z1bf = (unsigned short*)alloc((size_t)BSZ * INNER * 2);
    unsigned short* hbufbf = (unsigned short*)alloc((size_t)BSZ * HID * 2);
    unsigned short* projb = (unsigned short*)alloc((size_t)BSZ * NCLS * RANK * 2);
    unsigned short* gnnT = (unsigned short*)alloc((size_t)3 * GDIM * GDIM * 2);
    unsigned short* postT = (unsigned short*)alloc((size_t)GDIM * GDIM * 2);
    unsigned short* pinT = (unsigned short*)alloc((size_t)HID * GDIM * 2);
    unsigned short* w1T = (unsigned short*)alloc((size_t)6 * INNER * HID * 2);
    unsigned short* w2T = (unsigned short*)alloc((size_t)6 * HID * INNER * 2);
    unsigned short* poutT = (unsigned short*)alloc((size_t)NCLS * RANK * HID * 2);
    unsigned short* geneb = (unsigned short*)alloc((size_t)NGENES * RANK * 2);

    const int EB = (NEDGES + 255) / 256;
    const int NB = (NNODES + 255) / 256;

    // weight conversions
    tconv_k<<<dim3(GDIM / 32, GDIM / 32, 3), dim3(32, 8), 0, stream>>>(gnn_w, gnnT, GDIM, GDIM);
    tconv_k<<<dim3(GDIM / 32, GDIM / 32, 1), dim3(32, 8), 0, stream>>>(post_w, postT, GDIM, GDIM);
    tconv_k<<<dim3(HID / 32, GDIM / 32, 1), dim3(32, 8), 0, stream>>>(pin_w, pinT, GDIM, HID);
    tconv_k<<<dim3(INNER / 32, HID / 32, 6), dim3(32, 8), 0, stream>>>(blk_w1, w1T, HID, INNER);
    tconv_k<<<dim3(HID / 32, INNER / 32, 6), dim3(32, 8), 0, stream>>>(blk_w2, w2T, INNER, HID);
    tconv_k<<<dim3((NCLS * RANK) / 32, HID / 32, 1), dim3(32, 8), 0, stream>>>(pout_w, poutT, HID,
                                                                               NCLS * RANK);
    cvtb_k<<<(NGENES * RANK / 8 + 255) / 256, 256, 0, stream>>>(gene, geneb, NGENES * RANK / 8);

    // CSR build
    hipMemsetAsync(counts, 0, NNODES * 4, stream);
    hist_k<<<EB, 256, 0, stream>>>(edge_dst, counts, NEDGES);
    scan1_k<<<NB, 256, 0, stream>>>(counts, incl, bsums, NNODES);
    scan2_k<<<1, 128, 0, stream>>>(bsums, boffs, NB);
    scan3_k<<<NB, 256, 0, stream>>>(incl, counts, boffs, row_start, cursor, NNODES);
    scatter_k<<<EB, 256, 0, stream>>>(edge_src, edge_dst, edge_w, cursor, epack, NEDGES);

    // GNN layers 1 & 2 (full), layer 3 (selective: only 256 consumed rows)
    const float* x_in = partial_emb;
    float* bufs[2] = {xa, xb};
    for (int i = 0; i < 2; i++) {
        lnb_k<<<(NNODES + 3) / 4, 256, 0, stream>>>(x_in, gnn_ln_s + i * GDIM,
                                                    gnn_ln_b + i * GDIM, ln_bf, NNODES);
        aggb_k<<<(NNODES + 3) / 4, 256, 0, stream>>>(row_start, counts, epack, ln_bf, aggbf,
                                                     NNODES);
        float* x_out = bufs[i];
        mgemm_k<1, true, true><<<dim3(GDIM / 128, (NNODES + 127) / 128), 256, 0, stream>>>(
            aggbf, gnnT + (size_t)i * GDIM * GDIM, gnn_b + i * GDIM, x_in, x_out, NNODES, GDIM,
            GDIM);
        x_in = x_out;
    }
    // layer 3: LN full (neighbors arbitrary), aggregate only selected rows, tiny GEMM
    lnb_k<<<(NNODES + 3) / 4, 256, 0, stream>>>(xb, gnn_ln_s + 2 * GDIM, gnn_ln_b + 2 * GDIM,
                                                ln_bf, NNODES);
    aggsel_k<<<BSZ / 4, 256, 0, stream>>>(node_indices, row_start, counts, epack, ln_bf, aggselb);
    // x3[sel] = relu(aggsel @ W3 + b3) + x2[sel]  -> bf16
    mfull_k<1, 2><<<dim3(GDIM / 64, BSZ / 64), 256, 0, stream>>>(
        aggselb, gnnT + (size_t)2 * GDIM * GDIM, gnn_b + 2 * GDIM, node_indices, xb, pertinbf,
        BSZ, GDIM, GDIM);

    // post_mp + OOV replace (fused)
    mfull_k<0, 1><<<dim3(GDIM / 64, BSZ / 64), 256, 0, stream>>>(
        pertinbf, postT, post_b, node_indices, oov_emb, pertbf, BSZ, GDIM, GDIM);

    // pin -> hbuf (fp32) + LN(block0) -> zlnbf
    msk_k<<<dim3(HID / 64, BSZ / 64, 4), 256, 0, stream>>>(pertbf, pinT, part, BSZ, HID, GDIM,
                                                           GDIM / 4);
    redln_k<false, true><<<BSZ / 4, 256, 0, stream>>>(part, pin_b, blk_ln_s, blk_ln_b, hbuf,
                                                      zlnbf, 4);

    // 6 head blocks
    for (int i = 0; i < 6; i++) {
        // w1 full-K fused: bias + GELU -> bf16
        mfull_k<2, 0><<<dim3(INNER / 64, BSZ / 64), 256, 0, stream>>>(
            zlnbf, w1T + (size_t)i * INNER * HID, blk_b1 + i * INNER, nullptr, nullptr, z1bf, BSZ,
            INNER, HID);
        // w2 split-K (K=2048)
        msk_k<<<dim3(HID / 64, BSZ / 64, 8), 256, 0, stream>>>(
            z1bf, w2T + (size_t)i * HID * INNER, part, BSZ, HID, INNER, INNER / 8);
        if (i < 5) {
            redln_k<true, true><<<BSZ / 4, 256, 0, stream>>>(
                part, blk_b2 + i * HID, blk_ln_s + (i + 1) * HID, blk_ln_b + (i + 1) * HID, hbuf,
                zlnbf, 8);
        } else {
            redln_k<true, false><<<BSZ / 4, 256, 0, stream>>>(part, blk_b2 + i * HID, nullptr,
                                                              nullptr, hbuf, hbufbf, 8);
        }
    }

    // pout full-K fused: bias -> bf16
    mfull_k<0, 0><<<dim3((NCLS * RANK) / 64, BSZ / 64), 256, 0, stream>>>(
        hbufbf, poutT, pout_b, nullptr, nullptr, projb, BSZ, NCLS * RANK, HID);

    // logits
    mgemm_k<0, false, false><<<dim3((NGENES + 127) / 128, (BSZ * NCLS) / 128), 256, 0, stream>>>(
        projb, geneb, nullptr, nullptr, out, BSZ * NCLS, NGENES, RANK);
}